// Round 2
// baseline (6063.047 us; speedup 1.0000x reference)
//
#include <hip/hip_runtime.h>
#include <hip/hip_bf16.h>

// AgentMatchingDecoder on MI355X — round 2: correct f32, compact arena.
// Evidence-driven fixes vs round 1:
//  * out is f32 (out_npz 1.42 MB ≈ 393216 f32 compressed; bf16 raw is 0.79 MB)
//  * round-1 crash = SIGABRT (GPU memory fault) -> assume ws_size < 412 MB.
//    Arena now ~90 MiB: slot reuse + per-batch FFN/conv tower.
// Arena slots (floats):
//   A [0, 4.19M)        ks -> attn
//   B [4.19M, 8.39M)    qq -> {t0_b, x1_b, x3_b}
//   C [8.39M, 12.58M)   vs -> dec
//   D [12.58M, 20.97M)  sqs -> h1_b -> x2_b
//   W [20.97M, 23.36M)  reordered up0/up1/conv3 weights
//   S [23.36M, 23.58M)  qa, ka, s_as, s_qa, a_idx, q_idx

// ---------------------------------------------------------------- helpers
__device__ __forceinline__ void fma16(const float4 av, const float4 bv, float acc[4][4]) {
  acc[0][0] += av.x*bv.x; acc[0][1] += av.x*bv.y; acc[0][2] += av.x*bv.z; acc[0][3] += av.x*bv.w;
  acc[1][0] += av.y*bv.x; acc[1][1] += av.y*bv.y; acc[1][2] += av.y*bv.z; acc[1][3] += av.y*bv.w;
  acc[2][0] += av.z*bv.x; acc[2][1] += av.z*bv.y; acc[2][2] += av.z*bv.z; acc[2][3] += av.z*bv.w;
  acc[3][0] += av.w*bv.x; acc[3][1] += av.w*bv.y; acc[3][2] += av.w*bv.z; acc[3][3] += av.w*bv.w;
}

// ------------------------------------------------------- weight reorders
// up*_W (in=512, out=512, 2, 2) -> Wt[p][o][i], p = dy*2+dx  (K=i contiguous)
__global__ void reorder_upW_ker(const float* __restrict__ W, float* __restrict__ Wt) {
  int t = blockIdx.x * 256 + threadIdx.x;       // 4*512*512 = 1,048,576
  int i = t & 511, o = (t >> 9) & 511, p = t >> 18;
  Wt[t] = W[((size_t)(i * 512 + o)) * 4 + p];
}

// conv3_W (64, 512, 3, 3) -> Wt[o][tap*512+ci]  (K contiguous per row)
__global__ void reorder_c3W_ker(const float* __restrict__ W, float* __restrict__ Wt) {
  int t = blockIdx.x * 256 + threadIdx.x;       // 64*4608 = 294,912
  if (t >= 64 * 4608) return;
  int o = t / 4608, rem = t - o * 4608, tap = rem >> 9, ci = rem & 511;
  Wt[t] = W[((size_t)(o * 512 + ci)) * 9 + tap];
}

// ------------------------------------------------- GEMM NT: C = A * B^T
// A[M,K], B[N,K] row-major. MODE 0: C[r*N+c]. MODE 1: ConvTranspose2d(k2,s2)
// scatter: row r=(y,x) over Hin x Win (per-batch ptrs) -> [2y+dy, 2x+dx, c].
template<int MODE>
__global__ __launch_bounds__(256) void gemm_nt_ker(
    const float* __restrict__ A, const float* __restrict__ B,
    const float* __restrict__ bias, float* __restrict__ Cdst,
    int M, int N, int K, int relu, int Hin, int Win, int dy, int dx)
{
  __shared__ float As[16][68];
  __shared__ float Bs[16][68];
  const int tid = threadIdx.x;
  const int tx = tid & 15, ty = tid >> 4;
  const int bm = blockIdx.y * 64, bn = blockIdx.x * 64;
  const int lr = tid >> 2, lk = (tid & 3) << 2;
  const float* Ap = A + (size_t)(bm + lr) * K + lk;
  const float* Bp = B + (size_t)(bn + lr) * K + lk;
  float acc[4][4] = {};
  for (int k0 = 0; k0 < K; k0 += 16) {
    float4 a4 = *(const float4*)(Ap + k0);
    float4 b4 = *(const float4*)(Bp + k0);
    __syncthreads();
    As[lk+0][lr] = a4.x; As[lk+1][lr] = a4.y; As[lk+2][lr] = a4.z; As[lk+3][lr] = a4.w;
    Bs[lk+0][lr] = b4.x; Bs[lk+1][lr] = b4.y; Bs[lk+2][lr] = b4.z; Bs[lk+3][lr] = b4.w;
    __syncthreads();
#pragma unroll
    for (int k = 0; k < 16; ++k) {
      const float4 av = *(const float4*)&As[k][ty << 2];
      const float4 bv = *(const float4*)&Bs[k][tx << 2];
      fma16(av, bv, acc);
    }
  }
#pragma unroll
  for (int i = 0; i < 4; ++i) {
    const int row = bm + (ty << 2) + i;
#pragma unroll
    for (int j = 0; j < 4; ++j) {
      const int col = bn + (tx << 2) + j;
      float v = acc[i][j];
      if (bias) v += bias[col];
      if (relu) v = fmaxf(v, 0.f);
      if (MODE == 0) {
        Cdst[(size_t)row * N + col] = v;
      } else {
        const int y = row / Win, x = row - y * Win;
        const size_t o = (((size_t)(2 * y + dy)) * (2 * Win) + (2 * x + dx)) * N + col;
        Cdst[o] = v;
      }
    }
  }
}

// --------------------------------- batched GEMM TN: C[b] = S[b]^T * V[b]
// C[b,i,c] = sum_j S[b,j,i] * V[b,j,c]   (S: [B,K,M], V: [B,K,N])
__global__ __launch_bounds__(256) void gemm_tn_b_ker(
    const float* __restrict__ S, const float* __restrict__ V,
    float* __restrict__ Cdst, int M, int N, int K)
{
  __shared__ float As[16][68];
  __shared__ float Bs[16][68];
  const int tid = threadIdx.x;
  const int tx = tid & 15, ty = tid >> 4;
  const int bm = blockIdx.y * 64, bn = blockIdx.x * 64;
  const int b = blockIdx.z;
  const int jl = tid >> 4, cl = (tid & 15) << 2;
  const float* Sp = S + ((size_t)b * K + jl) * M + bm + cl;
  const float* Vp = V + ((size_t)b * K + jl) * N + bn + cl;
  float acc[4][4] = {};
  for (int k0 = 0; k0 < K; k0 += 16) {
    float4 a4 = *(const float4*)(Sp + (size_t)k0 * M);
    float4 b4 = *(const float4*)(Vp + (size_t)k0 * N);
    __syncthreads();
    *(float4*)&As[jl][cl] = a4;
    *(float4*)&Bs[jl][cl] = b4;
    __syncthreads();
#pragma unroll
    for (int k = 0; k < 16; ++k) {
      const float4 av = *(const float4*)&As[k][ty << 2];
      const float4 bv = *(const float4*)&Bs[k][tx << 2];
      fma16(av, bv, acc);
    }
  }
#pragma unroll
  for (int i = 0; i < 4; ++i)
#pragma unroll
    for (int j = 0; j < 4; ++j)
      Cdst[((size_t)b * M + bm + (ty << 2) + i) * N + bn + (tx << 2) + j] = acc[i][j];
}

// --------------------------- conv3x3 (NHWC per-batch, Cin=512, Cout=64, relu)
// gathered-K GEMM: K = 9*512, rows = 128x128 pixels, Wt[o][tap*512+ci]
__global__ __launch_bounds__(256) void conv3_ker(
    const float* __restrict__ X, const float* __restrict__ Wt, float* __restrict__ Y)
{
  __shared__ float As[16][68];
  __shared__ float Bs[16][68];
  const int tid = threadIdx.x;
  const int tx = tid & 15, ty = tid >> 4;
  const int bm = blockIdx.y * 64;
  const int lr = tid >> 2, lk = (tid & 3) << 2;
  const int r = bm + lr;
  const int y = r >> 7, x = r & 127;
  const float* Bp = Wt + (size_t)lr * 4608 + lk;
  float acc[4][4] = {};
  for (int k0 = 0; k0 < 4608; k0 += 16) {
    const int tap = k0 >> 9;
    const int yy = y + tap / 3 - 1, xx = x + tap % 3 - 1;
    float4 a4 = make_float4(0.f, 0.f, 0.f, 0.f);
    if ((unsigned)yy < 128u && (unsigned)xx < 128u)
      a4 = *(const float4*)(X + (((size_t)yy * 128 + xx)) * 512 + (k0 & 511) + lk);
    float4 b4 = *(const float4*)(Bp + k0);
    __syncthreads();
    As[lk+0][lr] = a4.x; As[lk+1][lr] = a4.y; As[lk+2][lr] = a4.z; As[lk+3][lr] = a4.w;
    Bs[lk+0][lr] = b4.x; Bs[lk+1][lr] = b4.y; Bs[lk+2][lr] = b4.z; Bs[lk+3][lr] = b4.w;
    __syncthreads();
#pragma unroll
    for (int k = 0; k < 16; ++k) {
      const float4 av = *(const float4*)&As[k][ty << 2];
      const float4 bv = *(const float4*)&Bs[k][tx << 2];
      fma16(av, bv, acc);
    }
  }
#pragma unroll
  for (int i = 0; i < 4; ++i)
#pragma unroll
    for (int j = 0; j < 4; ++j)
      Y[(size_t)(bm + (ty << 2) + i) * 64 + (tx << 2) + j] = fmaxf(acc[i][j], 0.f);
}

// --------------- conv3x3 final (NHWC per-batch in, Cin=64, Cout=3, f32 out)
__global__ void conv1_ker(
    const float* __restrict__ X, const float* __restrict__ Wsrc,
    float* __restrict__ Out)
{
  __shared__ float Wl[9 * 64 * 3];                 // [tap][ci][o]
  for (int i = threadIdx.x; i < 1728; i += 256) {
    int o = i / 576, rem = i - o * 576, ci = rem / 9, tap = rem - ci * 9;
    Wl[(tap * 64 + ci) * 3 + o] = Wsrc[((size_t)(o * 64 + ci)) * 9 + tap];
  }
  __syncthreads();
  const int pix = blockIdx.x * 256 + threadIdx.x;  // 16384 per batch
  const int y = pix >> 7, x = pix & 127;
  float acc0 = 0.f, acc1 = 0.f, acc2 = 0.f;
#pragma unroll
  for (int tap = 0; tap < 9; ++tap) {
    const int yy = y + tap / 3 - 1, xx = x + tap % 3 - 1;
    if ((unsigned)yy >= 128u || (unsigned)xx >= 128u) continue;
    const float* p = X + ((size_t)yy * 128 + xx) * 64;
    const float* w = &Wl[tap * 192];
#pragma unroll
    for (int ci = 0; ci < 64; ci += 4) {
      float4 v = *(const float4*)(p + ci);
      acc0 += v.x*w[(ci+0)*3+0] + v.y*w[(ci+1)*3+0] + v.z*w[(ci+2)*3+0] + v.w*w[(ci+3)*3+0];
      acc1 += v.x*w[(ci+0)*3+1] + v.y*w[(ci+1)*3+1] + v.z*w[(ci+2)*3+1] + v.w*w[(ci+3)*3+1];
      acc2 += v.x*w[(ci+0)*3+2] + v.y*w[(ci+1)*3+2] + v.z*w[(ci+2)*3+2] + v.w*w[(ci+3)*3+2];
    }
  }
  const size_t base = (size_t)y * 128 + x;
  Out[base]         = acc0;
  Out[base + 16384] = acc1;
  Out[base + 32768] = acc2;
}

// ------------------------------------------------ scores: 8-agent dots
// asFirst=1: Out[b,a,h]; asFirst=0: Out[b,h,a].  val = dot(X8[b,a],Y[b,h])/8
__global__ void scores8_ker(const float* __restrict__ X8, const float* __restrict__ Y,
                            float* __restrict__ Out, int asFirst)
{
  const int t = blockIdx.x * 256 + threadIdx.x;    // 65536
  const int a = t & 7, h = (t >> 3) & 1023, b = t >> 13;
  const float* xp = X8 + (size_t)(b * 8 + a) * 512;
  const float* yp = Y + ((size_t)b * 1024 + h) * 512;
  float s = 0.f;
  for (int k = 0; k < 512; k += 4) {
    float4 xv = *(const float4*)(xp + k);
    float4 yv = *(const float4*)(yp + k);
    s += xv.x*yv.x + xv.y*yv.y + xv.z*yv.z + xv.w*yv.w;
  }
  s *= 0.125f;
  Out[asFirst ? ((size_t)(b * 8 + a) * 1024 + h) : ((size_t)(b * 1024 + h) * 8 + a)] = s;
}

__global__ void argmax_ker(const float* __restrict__ s_as, const float* __restrict__ s_qa,
                           int* __restrict__ a_idx, int* __restrict__ q_idx)
{
  const int t = blockIdx.x * 256 + threadIdx.x;
  if (t >= 8192) return;
  const int b = t >> 10, h = t & 1023;
  {
    const float* p = s_as + (size_t)b * 8192 + h;  // stride 1024 over a
    float best = p[0]; int bi = 0;
#pragma unroll
    for (int a = 1; a < 8; ++a) { float v = p[(size_t)a * 1024]; if (v > best) { best = v; bi = a; } }
    a_idx[t] = bi;
  }
  {
    const float* p = s_qa + (size_t)t * 8;
    float best = p[0]; int bi = 0;
#pragma unroll
    for (int a = 1; a < 8; ++a) { float v = p[a]; if (v > best) { best = v; bi = a; } }
    q_idx[t] = bi;
  }
}

// ----------------- M = s_sa @ s_aq (+ align bias) then row-softmax over j
__global__ __launch_bounds__(1024) void softmax_ker(
    const float* __restrict__ s_as, const float* __restrict__ s_qa,
    const int* __restrict__ a_idx, const int* __restrict__ q_idx,
    float* __restrict__ Out)
{
  const int bh = blockIdx.x;                      // b*1024 + h
  const int b = bh >> 10, h = bh & 1023;
  const int j = threadIdx.x;
  __shared__ float red[16];
  __shared__ float sval;
  float u[8];
#pragma unroll
  for (int a = 0; a < 8; ++a) u[a] = s_as[((size_t)(b * 8 + a)) * 1024 + h];
  const int ai = a_idx[bh];
  const float* qrow = s_qa + ((size_t)(b * 1024 + j)) * 8;
  float m = 0.f;
#pragma unroll
  for (int a = 0; a < 8; ++a) m += u[a] * qrow[a];
  if (q_idx[b * 1024 + j] != ai) m -= 1e6f;
  const int lane = j & 63, wid = j >> 6;
  float mx = m;
  for (int off = 32; off; off >>= 1) mx = fmaxf(mx, __shfl_down(mx, off));
  if (lane == 0) red[wid] = mx;
  __syncthreads();
  if (j == 0) { float v = red[0]; for (int i = 1; i < 16; ++i) v = fmaxf(v, red[i]); sval = v; }
  __syncthreads();
  const float MX = sval;
  const float p = __expf(m - MX);
  float sm = p;
  for (int off = 32; off; off >>= 1) sm += __shfl_down(sm, off);
  if (lane == 0) red[wid] = sm;
  __syncthreads();
  if (j == 0) { float v = 0.f; for (int i = 0; i < 16; ++i) v += red[i]; sval = v; }
  __syncthreads();
  Out[(size_t)bh * 1024 + j] = p / sval;
}

// ---------- dec_b (512ch x 32x32 raw reinterpret) -> NHWC (32,32,512), per-b
__global__ void nchw_to_nhwc_ker(const float* __restrict__ src, float* __restrict__ dst)
{
  __shared__ float tile[32][33];
  const int p0 = blockIdx.x * 32, c0 = blockIdx.y * 32;
  const int tx = threadIdx.x & 31, ty = threadIdx.x >> 5;   // 32 x 8
  for (int i = ty; i < 32; i += 8)
    tile[i][tx] = src[((size_t)(c0 + i)) * 1024 + p0 + tx];
  __syncthreads();
  for (int i = ty; i < 32; i += 8)
    dst[((size_t)(p0 + i)) * 512 + c0 + tx] = tile[tx][i];
}

// ================================================================ launch
extern "C" void kernel_launch(void* const* d_in, const int* in_sizes, int n_in,
                              void* d_out, int out_size, void* d_ws, size_t ws_size,
                              hipStream_t stream)
{
  (void)in_sizes; (void)n_in; (void)out_size; (void)ws_size;
  const float* tok    = (const float*)d_in[0];
  const float* supp   = (const float*)d_in[1];
  const float* query  = (const float*)d_in[2];
  const float* qa_W   = (const float*)d_in[3];  const float* qa_b  = (const float*)d_in[4];
  const float* ks_W   = (const float*)d_in[5];  const float* ks_b  = (const float*)d_in[6];
  const float* ka_W   = (const float*)d_in[7];  const float* ka_b  = (const float*)d_in[8];
  const float* vs_W   = (const float*)d_in[9];  const float* vs_b  = (const float*)d_in[10];
  const float* ffn_W1 = (const float*)d_in[11]; const float* ffn_b1= (const float*)d_in[12];
  const float* ffn_W2 = (const float*)d_in[13]; const float* ffn_b2= (const float*)d_in[14];
  const float* up0_W  = (const float*)d_in[15]; const float* up0_b = (const float*)d_in[16];
  const float* up1_W  = (const float*)d_in[17]; const float* up1_b = (const float*)d_in[18];
  const float* c3_W   = (const float*)d_in[19]; const float* c1_W  = (const float*)d_in[20];
  float* out = (float*)d_out;                     // f32 output (npz-size evidence)

  float* ws = (float*)d_ws;
  const size_t SZ = 4194304;                      // 8*1024*512 floats
  float* slotA = ws;                              // ks -> attn
  float* slotB = ws + SZ;                         // qq -> {t0_b, x1_b, x3_b}
  float* slotC = ws + 2 * SZ;                     // vs -> dec
  float* slotD = ws + 3 * SZ;                     // sqs -> h1_b -> x2_b (8,388,608)
  float* W0t   = ws + 3 * SZ + 8388608;           // 20,971,520
  float* W1t   = W0t + 1048576;
  float* W3t   = W1t + 1048576;                   // +294,912
  float* qa    = W3t + 294912;                    // 23,363,584
  float* ka    = qa + 32768;
  float* s_as  = ka + 32768;
  float* s_qa  = s_as + 65536;
  int*   a_idx = (int*)(s_qa + 65536);
  int*   q_idx = a_idx + 8192;                    // ends ~23.58M floats = 90.2 MiB

  float* ks  = slotA;  float* attn = slotA;
  float* qq  = slotB;
  float* vs  = slotC;  float* dec  = slotC;
  float* sqs = slotD;

  // weight reorders
  reorder_upW_ker<<<4096, 256, 0, stream>>>(up0_W, W0t);
  reorder_upW_ker<<<4096, 256, 0, stream>>>(up1_W, W1t);
  reorder_c3W_ker<<<1152, 256, 0, stream>>>(c3_W, W3t);

  // projections (qq uses qa_linear, faithful to reference)
  gemm_nt_ker<0><<<dim3(8, 1),   256, 0, stream>>>(tok,   qa_W, qa_b, qa, 64,   512, 512, 0, 0,0,0,0);
  gemm_nt_ker<0><<<dim3(8, 1),   256, 0, stream>>>(tok,   ka_W, ka_b, ka, 64,   512, 512, 0, 0,0,0,0);
  gemm_nt_ker<0><<<dim3(8, 128), 256, 0, stream>>>(supp,  ks_W, ks_b, ks, 8192, 512, 512, 0, 0,0,0,0);
  gemm_nt_ker<0><<<dim3(8, 128), 256, 0, stream>>>(query, qa_W, qa_b, qq, 8192, 512, 512, 0, 0,0,0,0);
  gemm_nt_ker<0><<<dim3(8, 128), 256, 0, stream>>>(supp,  vs_W, vs_b, vs, 8192, 512, 512, 0, 0,0,0,0);

  scores8_ker<<<256, 256, 0, stream>>>(qa, ks, s_as, 1);
  scores8_ker<<<256, 256, 0, stream>>>(ka, qq, s_qa, 0);
  argmax_ker<<<32, 256, 0, stream>>>(s_as, s_qa, a_idx, q_idx);
  softmax_ker<<<8192, 1024, 0, stream>>>(s_as, s_qa, a_idx, q_idx, sqs);  // ks,qq now dead

  // attn[b,i,c] = sum_j sqs[b,j,i] * vs[b,j,c]   (attn overwrites ks slot)
  gemm_tn_b_ker<<<dim3(8, 16, 8), 256, 0, stream>>>(sqs, vs, attn, 1024, 512, 1024);
  // sqs, vs now dead

  // per-batch: FFN + conv tower in reused slots
  float* h1_b = slotD;                            // 2,097,152 (sqs dead)
  float* t0_b = slotB;                            // 524,288   (qq dead)
  float* x1_b = slotB + 524288;                   // 2,097,152
  float* x3_b = slotB + 2621440;                  // 1,048,576
  float* x2_b = slotD;                            // 8,388,608 (h1_b dead by then)

  for (int b = 0; b < 8; ++b) {
    const float* attn_b = attn + (size_t)b * 524288;
    float*       dec_b  = dec  + (size_t)b * 524288;
    float*       out_b  = out  + (size_t)b * 49152;

    gemm_nt_ker<0><<<dim3(32, 16), 256, 0, stream>>>(attn_b, ffn_W1, ffn_b1, h1_b, 1024, 2048, 512, 1, 0,0,0,0);
    gemm_nt_ker<0><<<dim3(8, 16),  256, 0, stream>>>(h1_b, ffn_W2, ffn_b2, dec_b, 1024, 512, 2048, 0, 0,0,0,0);

    // raw reinterpret (1024,512)->(512,32,32); transpose to NHWC
    nchw_to_nhwc_ker<<<dim3(32, 16), 256, 0, stream>>>(dec_b, t0_b);

    for (int p = 0; p < 4; ++p)
      gemm_nt_ker<1><<<dim3(8, 16), 256, 0, stream>>>(t0_b, W0t + (size_t)p * 262144, up0_b, x1_b,
                                                      1024, 512, 512, 0, 32, 32, p >> 1, p & 1);
    for (int p = 0; p < 4; ++p)
      gemm_nt_ker<1><<<dim3(8, 64), 256, 0, stream>>>(x1_b, W1t + (size_t)p * 262144, up1_b, x2_b,
                                                      4096, 512, 512, 0, 64, 64, p >> 1, p & 1);

    conv3_ker<<<dim3(1, 256), 256, 0, stream>>>(x2_b, W3t, x3_b);
    conv1_ker<<<64, 256, 0, stream>>>(x3_b, c1_W, out_b);
  }
}

// Round 3
// 1584.715 us; speedup vs baseline: 3.8260x; 3.8260x over previous
//
#include <hip/hip_runtime.h>

// AgentMatchingDecoder on MI355X — round 3: bf16 MFMA for all heavy GEMMs.
// f32 kept for the argmax-critical score path (qa/ka/ks/qq + scores).
// Arena stays under the round-2-proven 94.3 MB.
//
// Arena (float offsets):
//   weights bf16 [0 .. 2,375,680) ; smalls ; zbuf(4KB)
//   S1 @ 2,589,696 (4,194,304 f): ks_f32 | sqsT | dec | {x3, x3T}
//   S2 @ 6,784,000 (4,194,304 f): qq_f32 | sqs_bf | x2[pair] part
//   S3 @10,978,304 (2,097,152 f): supp_bf | vsT | t0 | x2 part
//   S4 @13,075,456 (2,097,152 f): vs_bf | attn | x2 part
//   S5 @15,172,608 (8,388,608 f): h1 | x1         (end 23,561,216 f = 94.24 MB)

using short8 = __attribute__((ext_vector_type(8))) short;   // 8 bf16 (4 VGPR)
using f32x4  = __attribute__((ext_vector_type(4))) float;   // MFMA acc

__device__ __forceinline__ unsigned short f2bf(float f) {
  unsigned int u = __float_as_uint(f);
  return (unsigned short)((u + 0x7FFFu + ((u >> 16) & 1u)) >> 16);
}
__device__ __forceinline__ float bf2f(unsigned short h) {
  return __uint_as_float(((unsigned int)h) << 16);
}
__device__ __forceinline__ void stage16(const unsigned short* g, unsigned short* l) {
  __builtin_amdgcn_global_load_lds(
      (const __attribute__((address_space(1))) unsigned int*)g,
      (__attribute__((address_space(3))) unsigned int*)l, 16, 0, 0);
}
// LDS slot swizzle: involution over the 4 16-byte slots of a 64B tile row.
__device__ __forceinline__ int swz(int r) { return (r & 3) ^ ((r >> 2) & 3); }

// ------------------------------------------------------------ converts
__global__ void cvt_bf_ker(const float* __restrict__ in, unsigned short* __restrict__ out, int n4) {
  int i = blockIdx.x * 256 + threadIdx.x;
  if (i >= n4) return;
  float4 v = ((const float4*)in)[i];
  unsigned int lo = (unsigned int)f2bf(v.x) | ((unsigned int)f2bf(v.y) << 16);
  unsigned int hi = (unsigned int)f2bf(v.z) | ((unsigned int)f2bf(v.w) << 16);
  ((uint2*)out)[i] = make_uint2(lo, hi);
}

// up*_W (in=512,out=512,2,2) -> bf16 Wt[p][o][i], p = dy*2+dx
__global__ void reorder_up_bf_ker(const float* __restrict__ W, unsigned short* __restrict__ Wt) {
  int t = blockIdx.x * 256 + threadIdx.x;       // 1,048,576
  int i = t & 511, o = (t >> 9) & 511, p = t >> 18;
  Wt[t] = f2bf(W[((size_t)(i * 512 + o)) * 4 + p]);
}

// conv3_W (64,512,3,3) -> bf16 Wt[o][tap*512+ci]
__global__ void reorder_c3_bf_ker(const float* __restrict__ W, unsigned short* __restrict__ Wt) {
  int t = blockIdx.x * 256 + threadIdx.x;       // 294,912
  if (t >= 64 * 4608) return;
  int o = t / 4608, rem = t - o * 4608, tap = rem >> 9, ci = rem & 511;
  Wt[t] = f2bf(W[((size_t)(o * 512 + ci)) * 9 + tap]);
}

// ------------------------------------------- f32 GEMM NT (score path only)
__device__ __forceinline__ void fma16(const float4 av, const float4 bv, float acc[4][4]) {
  acc[0][0] += av.x*bv.x; acc[0][1] += av.x*bv.y; acc[0][2] += av.x*bv.z; acc[0][3] += av.x*bv.w;
  acc[1][0] += av.y*bv.x; acc[1][1] += av.y*bv.y; acc[1][2] += av.y*bv.z; acc[1][3] += av.y*bv.w;
  acc[2][0] += av.z*bv.x; acc[2][1] += av.z*bv.y; acc[2][2] += av.z*bv.z; acc[2][3] += av.z*bv.w;
  acc[3][0] += av.w*bv.x; acc[3][1] += av.w*bv.y; acc[3][2] += av.w*bv.z; acc[3][3] += av.w*bv.w;
}
__global__ __launch_bounds__(256) void gemm_nt_f32_ker(
    const float* __restrict__ A, const float* __restrict__ B,
    const float* __restrict__ bias, float* __restrict__ C, int M, int N, int K)
{
  __shared__ float As[16][68];
  __shared__ float Bs[16][68];
  const int tid = threadIdx.x;
  const int tx = tid & 15, ty = tid >> 4;
  const int bm = blockIdx.y * 64, bn = blockIdx.x * 64;
  const int lr = tid >> 2, lk = (tid & 3) << 2;
  const float* Ap = A + (size_t)(bm + lr) * K + lk;
  const float* Bp = B + (size_t)(bn + lr) * K + lk;
  float acc[4][4] = {};
  for (int k0 = 0; k0 < K; k0 += 16) {
    float4 a4 = *(const float4*)(Ap + k0);
    float4 b4 = *(const float4*)(Bp + k0);
    __syncthreads();
    As[lk+0][lr] = a4.x; As[lk+1][lr] = a4.y; As[lk+2][lr] = a4.z; As[lk+3][lr] = a4.w;
    Bs[lk+0][lr] = b4.x; Bs[lk+1][lr] = b4.y; Bs[lk+2][lr] = b4.z; Bs[lk+3][lr] = b4.w;
    __syncthreads();
#pragma unroll
    for (int k = 0; k < 16; ++k) {
      const float4 av = *(const float4*)&As[k][ty << 2];
      const float4 bv = *(const float4*)&Bs[k][tx << 2];
      fma16(av, bv, acc);
    }
  }
#pragma unroll
  for (int i = 0; i < 4; ++i)
#pragma unroll
    for (int j = 0; j < 4; ++j) {
      const int row = bm + (ty << 2) + i, col = bn + (tx << 2) + j;
      C[(size_t)row * N + col] = acc[i][j] + bias[col];
    }
}

// ---------------------------------------------- bf16 MFMA GEMM NT (+scatter)
// C = A[M,K] * B[N,K]^T (+bias, relu). bf16 in/out, f32 accum.
// BM=128, BN=128, BK=32; 4 waves (2x2), each 4x4 frags of 16x16x32.
// MODE 0: C[row*N+col]. MODE 1: ConvT2d(k2,s2) scatter (per-batch pixel rows).
template<int MODE>
__global__ __launch_bounds__(256) void mfma_nt_ker(
    const unsigned short* __restrict__ A, const unsigned short* __restrict__ B,
    const float* __restrict__ bias, unsigned short* __restrict__ C,
    int M, int N, int K, int relu,
    long sA, long sB, long sC,
    int pixShift, int winShift, long outBS, int dy, int dx)
{
  (void)M;
  __shared__ __align__(16) unsigned short As[128 * 32];
  __shared__ __align__(16) unsigned short Bs[128 * 32];
  const int tid = threadIdx.x, wave = tid >> 6, lane = tid & 63;
  const int wm = wave >> 1, wn = wave & 1;
  const int bm = blockIdx.y * 128, bn = blockIdx.x * 128;
  const int z = blockIdx.z;
  const unsigned short* Az = A + (size_t)z * sA;
  const unsigned short* Bz = B + (size_t)z * sB;

  f32x4 zero4 = {0.f, 0.f, 0.f, 0.f};
  f32x4 acc[4][4];
#pragma unroll
  for (int i = 0; i < 4; ++i)
#pragma unroll
    for (int j = 0; j < 4; ++j) acc[i][j] = zero4;

  for (int k0 = 0; k0 < K; k0 += 32) {
    __syncthreads();
#pragma unroll
    for (int q = 0; q < 2; ++q) {
      int idx = q * 256 + tid;
      int rr = idx >> 2, s = idx & 3;
      stage16(Az + (size_t)(bm + rr) * K + k0 + ((s ^ swz(rr)) << 3),
              &As[(q * 256 + wave * 64) * 8]);
    }
#pragma unroll
    for (int q = 0; q < 2; ++q) {
      int idx = q * 256 + tid;
      int rr = idx >> 2, s = idx & 3;
      stage16(Bz + (size_t)(bn + rr) * K + k0 + ((s ^ swz(rr)) << 3),
              &Bs[(q * 256 + wave * 64) * 8]);
    }
    __syncthreads();
    short8 af[4], bf[4];
#pragma unroll
    for (int mt = 0; mt < 4; ++mt) {
      int r = wm * 64 + mt * 16 + (lane & 15);
      int s = (lane >> 4) ^ swz(r);
      af[mt] = *(const short8*)&As[r * 32 + s * 8];
    }
#pragma unroll
    for (int nt = 0; nt < 4; ++nt) {
      int r = wn * 64 + nt * 16 + (lane & 15);
      int s = (lane >> 4) ^ swz(r);
      bf[nt] = *(const short8*)&Bs[r * 32 + s * 8];
    }
#pragma unroll
    for (int mt = 0; mt < 4; ++mt)
#pragma unroll
      for (int nt = 0; nt < 4; ++nt)
        acc[mt][nt] = __builtin_amdgcn_mfma_f32_16x16x32_bf16(af[mt], bf[nt], acc[mt][nt], 0, 0, 0);
  }
  unsigned short* Cz = C + (size_t)z * sC;
#pragma unroll
  for (int mt = 0; mt < 4; ++mt)
#pragma unroll
    for (int nt = 0; nt < 4; ++nt)
#pragma unroll
      for (int q = 0; q < 4; ++q) {
        int row = bm + wm * 64 + mt * 16 + ((lane >> 4) << 2) + q;
        int col = bn + wn * 64 + nt * 16 + (lane & 15);
        float v = acc[mt][nt][q];
        if (bias) v += bias[col];
        if (relu) v = fmaxf(v, 0.f);
        if (MODE == 0) {
          Cz[(size_t)row * N + col] = f2bf(v);
        } else {
          int bb = row >> pixShift;
          int pix = row & ((1 << pixShift) - 1);
          int y = pix >> winShift, x = pix & ((1 << winShift) - 1);
          int yy = 2 * y + dy, xx = 2 * x + dx;
          long o = (long)bb * outBS + ((long)yy * (2 << winShift) + xx) * (long)N + col;
          Cz[o] = f2bf(v);
        }
      }
}

// ----------------------- conv3x3 MFMA (per 2 batches): gathered-A GEMM
// X: x2 [2][128][128][512] bf16 (NHWC, unpadded); Wt: [64][4608] bf16;
// Y: [32768][64] bf16, relu. BM=128 (one pixel row), BN=64, K=4608.
__global__ __launch_bounds__(256) void mfma_conv3_ker(
    const unsigned short* __restrict__ X, const unsigned short* __restrict__ Wt,
    unsigned short* __restrict__ Y, const unsigned short* __restrict__ zbuf)
{
  __shared__ __align__(16) unsigned short As[128 * 32];
  __shared__ __align__(16) unsigned short Bs[64 * 32];
  const int tid = threadIdx.x, wave = tid >> 6, lane = tid & 63;
  const int wm = wave >> 1, wn = wave & 1;
  const int bm = blockIdx.x * 128;
  const int bb = bm >> 14, y = (bm & 16383) >> 7;   // whole block = one (bb,y) row

  f32x4 zero4 = {0.f, 0.f, 0.f, 0.f};
  f32x4 acc[4][2];
#pragma unroll
  for (int i = 0; i < 4; ++i) { acc[i][0] = zero4; acc[i][1] = zero4; }

  for (int k0 = 0; k0 < 4608; k0 += 32) {
    const int tap = k0 >> 9, ci0 = k0 & 511;
    const int yy = y + tap / 3 - 1;
    const int xo = tap % 3 - 1;
    if ((unsigned)yy >= 128u) continue;             // whole-tile zero: skip (uniform)
    __syncthreads();
#pragma unroll
    for (int q = 0; q < 2; ++q) {
      int idx = q * 256 + tid;
      int rr = idx >> 2, s = idx & 3;
      int xx = rr + xo;
      const unsigned short* src;
      if ((unsigned)xx < 128u)
        src = X + ((((size_t)bb * 128 + yy) * 128 + xx) << 9) + ci0 + ((s ^ swz(rr)) << 3);
      else
        src = zbuf + ((idx & 127) << 3);            // zero-filled scratch
      stage16(src, &As[(q * 256 + wave * 64) * 8]);
    }
    {
      int rr = tid >> 2, s = tid & 3;
      stage16(Wt + (size_t)rr * 4608 + k0 + ((s ^ swz(rr)) << 3), &Bs[(wave * 64) * 8]);
    }
    __syncthreads();
    short8 af[4], bf[2];
#pragma unroll
    for (int mt = 0; mt < 4; ++mt) {
      int r = wm * 64 + mt * 16 + (lane & 15);
      int s = (lane >> 4) ^ swz(r);
      af[mt] = *(const short8*)&As[r * 32 + s * 8];
    }
#pragma unroll
    for (int nt = 0; nt < 2; ++nt) {
      int r = wn * 32 + nt * 16 + (lane & 15);
      int s = (lane >> 4) ^ swz(r);
      bf[nt] = *(const short8*)&Bs[r * 32 + s * 8];
    }
#pragma unroll
    for (int mt = 0; mt < 4; ++mt)
#pragma unroll
      for (int nt = 0; nt < 2; ++nt)
        acc[mt][nt] = __builtin_amdgcn_mfma_f32_16x16x32_bf16(af[mt], bf[nt], acc[mt][nt], 0, 0, 0);
  }
#pragma unroll
  for (int mt = 0; mt < 4; ++mt)
#pragma unroll
    for (int nt = 0; nt < 2; ++nt)
#pragma unroll
      for (int q = 0; q < 4; ++q) {
        int row = bm + wm * 64 + mt * 16 + ((lane >> 4) << 2) + q;
        int col = wn * 32 + nt * 16 + (lane & 15);
        Y[(size_t)row * 64 + col] = f2bf(fmaxf(acc[mt][nt][q], 0.f));
      }
}

// ------------------------------------------------ batched bf16 transpose
// in[z][R][C] -> out[z][C][R]
__global__ void transpose_bf_ker(const unsigned short* __restrict__ src,
                                 unsigned short* __restrict__ dst, int R, int C)
{
  __shared__ unsigned short tile[32][33];
  const size_t zo = (size_t)blockIdx.z * R * C;
  const int r0 = blockIdx.y * 32, c0 = blockIdx.x * 32;
  const int tx = threadIdx.x & 31, ty = threadIdx.x >> 5;   // 32 x 8
  for (int i = ty; i < 32; i += 8)
    tile[i][tx] = src[zo + (size_t)(r0 + i) * C + c0 + tx];
  __syncthreads();
  for (int i = ty; i < 32; i += 8)
    dst[zo + (size_t)(c0 + i) * R + r0 + tx] = tile[tx][i];
}

// ------------------------------------------------ scores / argmax / softmax
__global__ void scores8_ker(const float* __restrict__ X8, const float* __restrict__ Y,
                            float* __restrict__ Out, int asFirst)
{
  const int t = blockIdx.x * 256 + threadIdx.x;    // 65536
  const int a = t & 7, h = (t >> 3) & 1023, b = t >> 13;
  const float* xp = X8 + (size_t)(b * 8 + a) * 512;
  const float* yp = Y + ((size_t)b * 1024 + h) * 512;
  float s = 0.f;
  for (int k = 0; k < 512; k += 4) {
    float4 xv = *(const float4*)(xp + k);
    float4 yv = *(const float4*)(yp + k);
    s += xv.x*yv.x + xv.y*yv.y + xv.z*yv.z + xv.w*yv.w;
  }
  s *= 0.125f;
  Out[asFirst ? ((size_t)(b * 8 + a) * 1024 + h) : ((size_t)(b * 1024 + h) * 8 + a)] = s;
}

__global__ void argmax_ker(const float* __restrict__ s_as, const float* __restrict__ s_qa,
                           int* __restrict__ a_idx, int* __restrict__ q_idx)
{
  const int t = blockIdx.x * 256 + threadIdx.x;
  if (t >= 8192) return;
  const int b = t >> 10, h = t & 1023;
  {
    const float* p = s_as + (size_t)b * 8192 + h;
    float best = p[0]; int bi = 0;
#pragma unroll
    for (int a = 1; a < 8; ++a) { float v = p[(size_t)a * 1024]; if (v > best) { best = v; bi = a; } }
    a_idx[t] = bi;
  }
  {
    const float* p = s_qa + (size_t)t * 8;
    float best = p[0]; int bi = 0;
#pragma unroll
    for (int a = 1; a < 8; ++a) { float v = p[a]; if (v > best) { best = v; bi = a; } }
    q_idx[t] = bi;
  }
}

__global__ __launch_bounds__(1024) void softmax_ker(
    const float* __restrict__ s_as, const float* __restrict__ s_qa,
    const int* __restrict__ a_idx, const int* __restrict__ q_idx,
    unsigned short* __restrict__ Out)
{
  const int bh = blockIdx.x;                      // b*1024 + h
  const int b = bh >> 10, h = bh & 1023;
  const int j = threadIdx.x;
  __shared__ float red[16];
  __shared__ float sval;
  float u[8];
#pragma unroll
  for (int a = 0; a < 8; ++a) u[a] = s_as[((size_t)(b * 8 + a)) * 1024 + h];
  const int ai = a_idx[bh];
  const float* qrow = s_qa + ((size_t)(b * 1024 + j)) * 8;
  float m = 0.f;
#pragma unroll
  for (int a = 0; a < 8; ++a) m += u[a] * qrow[a];
  if (q_idx[b * 1024 + j] != ai) m -= 1e6f;
  const int lane = j & 63, wid = j >> 6;
  float mx = m;
  for (int off = 32; off; off >>= 1) mx = fmaxf(mx, __shfl_down(mx, off));
  if (lane == 0) red[wid] = mx;
  __syncthreads();
  if (j == 0) { float v = red[0]; for (int i = 1; i < 16; ++i) v = fmaxf(v, red[i]); sval = v; }
  __syncthreads();
  const float MX = sval;
  const float p = __expf(m - MX);
  float sm = p;
  for (int off = 32; off; off >>= 1) sm += __shfl_down(sm, off);
  if (lane == 0) red[wid] = sm;
  __syncthreads();
  if (j == 0) { float v = 0.f; for (int i = 0; i < 16; ++i) v += red[i]; sval = v; }
  __syncthreads();
  Out[(size_t)bh * 1024 + j] = f2bf(p / sval);
}

// -------- conv1 3x3 (Cin=64, Cout=3), channel-major bf16 input, f32 NCHW out
// X3T: [64][32768] bf16 (2 batches); Out: pair base, per-batch 3*16384 f32.
__global__ void conv1_ker(const unsigned short* __restrict__ X3T,
                          const float* __restrict__ Wsrc, float* __restrict__ Out)
{
  __shared__ float Wl[9 * 64 * 3];                 // [tap][ci][o]
  for (int i = threadIdx.x; i < 1728; i += 256) {
    int o = i / 576, rem = i - o * 576, ci = rem / 9, tap = rem - ci * 9;
    Wl[(tap * 64 + ci) * 3 + o] = Wsrc[((size_t)(o * 64 + ci)) * 9 + tap];
  }
  __syncthreads();
  const int pix2 = blockIdx.x * 256 + threadIdx.x; // 0..32767
  const int bl = pix2 >> 14, pix = pix2 & 16383, y = pix >> 7, x = pix & 127;
  float acc0 = 0.f, acc1 = 0.f, acc2 = 0.f;
#pragma unroll
  for (int tap = 0; tap < 9; ++tap) {
    const int yy = y + tap / 3 - 1, xx = x + tap % 3 - 1;
    if ((unsigned)yy >= 128u || (unsigned)xx >= 128u) continue;
    const size_t p = (size_t)bl * 16384 + (size_t)yy * 128 + xx;
    const float* w = &Wl[tap * 192];
#pragma unroll
    for (int ci = 0; ci < 64; ++ci) {
      float v = bf2f(X3T[(size_t)ci * 32768 + p]);
      acc0 += v * w[ci * 3 + 0];
      acc1 += v * w[ci * 3 + 1];
      acc2 += v * w[ci * 3 + 2];
    }
  }
  const size_t base = (size_t)bl * 49152 + (size_t)y * 128 + x;
  Out[base]         = acc0;
  Out[base + 16384] = acc1;
  Out[base + 32768] = acc2;
}

// ================================================================ launch
extern "C" void kernel_launch(void* const* d_in, const int* in_sizes, int n_in,
                              void* d_out, int out_size, void* d_ws, size_t ws_size,
                              hipStream_t stream)
{
  (void)in_sizes; (void)n_in; (void)out_size; (void)ws_size;
  const float* tok    = (const float*)d_in[0];
  const float* supp   = (const float*)d_in[1];
  const float* query  = (const float*)d_in[2];
  const float* qa_W   = (const float*)d_in[3];  const float* qa_b  = (const float*)d_in[4];
  const float* ks_W   = (const float*)d_in[5];  const float* ks_b  = (const float*)d_in[6];
  const float* ka_W   = (const float*)d_in[7];  const float* ka_b  = (const float*)d_in[8];
  const float* vs_W   = (const float*)d_in[9];  const float* vs_b  = (const float*)d_in[10];
  const float* ffn_W1 = (const float*)d_in[11]; const float* ffn_b1= (const float*)d_in[12];
  const float* ffn_W2 = (const float*)d_in[13]; const float* ffn_b2= (const float*)d_in[14];
  const float* up0_W  = (const float*)d_in[15]; const float* up0_b = (const float*)d_in[16];
  const float* up1_W  = (const float*)d_in[17]; const float* up1_b = (const float*)d_in[18];
  const float* c3_W   = (const float*)d_in[19]; const float* c1_W  = (const float*)d_in[20];
  float* out = (float*)d_out;

  float* F = (float*)d_ws;
  // persistent region
  unsigned short* vsWb   = (unsigned short*)(F + 0);
  unsigned short* ffnW1b = (unsigned short*)(F + 131072);
  unsigned short* ffnW2b = (unsigned short*)(F + 655360);
  unsigned short* up0t   = (unsigned short*)(F + 1179648);
  unsigned short* up1t   = (unsigned short*)(F + 1703936);
  unsigned short* c3t    = (unsigned short*)(F + 2228224);
  float* qa    = F + 2375680;
  float* ka    = F + 2408448;
  float* s_as  = F + 2441216;
  float* s_qa  = F + 2506752;
  int*   a_idx = (int*)(F + 2572288);
  int*   q_idx = (int*)(F + 2580480);
  unsigned short* zbuf = (unsigned short*)(F + 2588672);   // 4 KB, memset 0
  // slots
  float* ksF            = F + 2589696;                         // S1 (f32)
  unsigned short* sqsT  = (unsigned short*)(F + 2589696);      // S1
  unsigned short* dec   = (unsigned short*)(F + 2589696);      // S1
  unsigned short* x3    = (unsigned short*)(F + 2589696);      // S1 (pair)
  unsigned short* x3T   = (unsigned short*)(F + 2589696 + 1048576);
  float* qqF            = F + 6784000;                         // S2 (f32)
  unsigned short* sqs   = (unsigned short*)(F + 6784000);      // S2
  unsigned short* x2    = (unsigned short*)(F + 6784000);      // S2..S4 contiguous
  unsigned short* suppb = (unsigned short*)(F + 10978304);     // S3
  unsigned short* vsT   = (unsigned short*)(F + 10978304);     // S3
  unsigned short* t0    = (unsigned short*)(F + 10978304);     // S3
  unsigned short* vsb   = (unsigned short*)(F + 13075456);     // S4
  unsigned short* attn  = (unsigned short*)(F + 13075456);     // S4
  unsigned short* h1    = (unsigned short*)(F + 15172608);     // S5
  unsigned short* x1    = (unsigned short*)(F + 15172608);     // S5

  hipMemsetAsync(zbuf, 0, 4096, stream);

  // converts / reorders
  cvt_bf_ker<<<4096, 256, 0, stream>>>(supp,   suppb,  1048576);   // 4,194,304/4
  cvt_bf_ker<<<256,  256, 0, stream>>>(vs_W,   vsWb,   65536);
  cvt_bf_ker<<<1024, 256, 0, stream>>>(ffn_W1, ffnW1b, 262144);
  cvt_bf_ker<<<1024, 256, 0, stream>>>(ffn_W2, ffnW2b, 262144);
  reorder_up_bf_ker<<<4096, 256, 0, stream>>>(up0_W, up0t);
  reorder_up_bf_ker<<<4096, 256, 0, stream>>>(up1_W, up1t);
  reorder_c3_bf_ker<<<1152, 256, 0, stream>>>(c3_W, c3t);

  // f32 score path
  gemm_nt_f32_ker<<<dim3(8, 1),   256, 0, stream>>>(tok,   qa_W, qa_b, qa,  64,   512, 512);
  gemm_nt_f32_ker<<<dim3(8, 1),   256, 0, stream>>>(tok,   ka_W, ka_b, ka,  64,   512, 512);
  gemm_nt_f32_ker<<<dim3(8, 128), 256, 0, stream>>>(supp,  ks_W, ks_b, ksF, 8192, 512, 512);
  gemm_nt_f32_ker<<<dim3(8, 128), 256, 0, stream>>>(query, qa_W, qa_b, qqF, 8192, 512, 512);

  // vs projection (bf16 MFMA)
  mfma_nt_ker<0><<<dim3(4, 64, 1), 256, 0, stream>>>(suppb, vsWb, vs_b, vsb,
      8192, 512, 512, 0, 0, 0, 0, 0, 0, 0, 0, 0);

  scores8_ker<<<256, 256, 0, stream>>>(qa, ksF, s_as, 1);
  scores8_ker<<<256, 256, 0, stream>>>(ka, qqF, s_qa, 0);
  argmax_ker<<<32, 256, 0, stream>>>(s_as, s_qa, a_idx, q_idx);
  softmax_ker<<<8192, 1024, 0, stream>>>(s_as, s_qa, a_idx, q_idx, sqs);  // ks,qq dead

  // transposes for PV operands
  transpose_bf_ker<<<dim3(32, 32, 8), 256, 0, stream>>>(sqs, sqsT, 1024, 1024); // S2->S1
  transpose_bf_ker<<<dim3(16, 32, 8), 256, 0, stream>>>(vsb, vsT, 1024, 512);   // S4->S3

  // attn[b,i,c] = sum_j P[b,j,i] * vs[b,j,c]  (batched MFMA)
  mfma_nt_ker<0><<<dim3(4, 8, 8), 256, 0, stream>>>(sqsT, vsT, nullptr, attn,
      1024, 512, 1024, 0, 1024L*1024, 512L*1024, 1024L*512, 0, 0, 0, 0, 0);

  // FFN
  mfma_nt_ker<0><<<dim3(16, 64, 1), 256, 0, stream>>>(attn, ffnW1b, ffn_b1, h1,
      8192, 2048, 512, 1, 0, 0, 0, 0, 0, 0, 0, 0);
  mfma_nt_ker<0><<<dim3(4, 64, 1), 256, 0, stream>>>(h1, ffnW2b, ffn_b2, dec,
      8192, 512, 2048, 0, 0, 0, 0, 0, 0, 0, 0, 0);

  // dec raw-reinterpret (b,512,32,32) -> NHWC t0 [b][1024][512]
  transpose_bf_ker<<<dim3(32, 16, 8), 256, 0, stream>>>(dec, t0, 512, 1024);    // S1->S3

  // up0: 4 parity GEMMs, scatter to x1 [8][64][64][512]
  for (int p = 0; p < 4; ++p)
    mfma_nt_ker<1><<<dim3(4, 64, 1), 256, 0, stream>>>(t0, up0t + (size_t)p * 262144,
        up0_b, x1, 8192, 512, 512, 0, 0, 0, 0, 10, 5, 2097152L, p >> 1, p & 1);

  // per 2-batch pair: up1 -> x2, conv3 -> x3, transpose, conv1 -> out
  for (int pair = 0; pair < 4; ++pair) {
    const unsigned short* x1p = x1 + (size_t)pair * 4194304;
    for (int p = 0; p < 4; ++p)
      mfma_nt_ker<1><<<dim3(4, 64, 1), 256, 0, stream>>>(x1p, up1t + (size_t)p * 262144,
          up1_b, x2, 8192, 512, 512, 0, 0, 0, 0, 12, 6, 8388608L, p >> 1, p & 1);
    mfma_conv3_ker<<<256, 256, 0, stream>>>(x2, c3t, x3, zbuf);
    transpose_bf_ker<<<dim3(2, 1024, 1), 256, 0, stream>>>(x3, x3T, 32768, 64);
    conv1_ker<<<128, 256, 0, stream>>>(x3T, c1_W, out + (size_t)pair * 98304);
  }
}

// Round 7
// 1243.103 us; speedup vs baseline: 4.8773x; 1.2748x over previous
//
#include <hip/hip_runtime.h>

// AgentMatchingDecoder on MI355X — round 4 kernel (4th submit; rounds 4-6
// were infra failures: 2x GPUAcquisitionTimeout, 1x container-failed-twice;
// kernel has never executed):
//  * 2-phase double-buffered LDS pipeline in all MFMA kernels (T3-min recipe)
//  * ks/qq f32 GEMMs eliminated via associativity (qk = qa@ks_W, kq = ka@qa_W)
//  * ConvT parity loops merged into blockIdx.z (grid x4 => occupancy)
// Arena identical to round 3 (94.24 MB proven); qk/kq/cas/cqa alias S2 (dead
// before softmax writes sqs there).

using short8 = __attribute__((ext_vector_type(8))) short;   // 8 bf16 (4 VGPR)
using f32x4  = __attribute__((ext_vector_type(4))) float;   // MFMA acc

__device__ __forceinline__ unsigned short f2bf(float f) {
  unsigned int u = __float_as_uint(f);
  return (unsigned short)((u + 0x7FFFu + ((u >> 16) & 1u)) >> 16);
}
__device__ __forceinline__ float bf2f(unsigned short h) {
  return __uint_as_float(((unsigned int)h) << 16);
}
__device__ __forceinline__ void stage16(const unsigned short* g, unsigned short* l) {
  __builtin_amdgcn_global_load_lds(
      (const __attribute__((address_space(1))) unsigned int*)g,
      (__attribute__((address_space(3))) unsigned int*)l, 16, 0, 0);
}
// LDS slot swizzle: involution over the 4 16-byte slots of a 64B tile row.
__device__ __forceinline__ int swz(int r) { return (r & 3) ^ ((r >> 2) & 3); }

// ------------------------------------------------------------ converts
__global__ void cvt_bf_ker(const float* __restrict__ in, unsigned short* __restrict__ out, int n4) {
  int i = blockIdx.x * 256 + threadIdx.x;
  if (i >= n4) return;
  float4 v = ((const float4*)in)[i];
  unsigned int lo = (unsigned int)f2bf(v.x) | ((unsigned int)f2bf(v.y) << 16);
  unsigned int hi = (unsigned int)f2bf(v.z) | ((unsigned int)f2bf(v.w) << 16);
  ((uint2*)out)[i] = make_uint2(lo, hi);
}

// up*_W (in=512,out=512,2,2) -> bf16 Wt[p][o][i], p = dy*2+dx
__global__ void reorder_up_bf_ker(const float* __restrict__ W, unsigned short* __restrict__ Wt) {
  int t = blockIdx.x * 256 + threadIdx.x;       // 1,048,576
  int i = t & 511, o = (t >> 9) & 511, p = t >> 18;
  Wt[t] = f2bf(W[((size_t)(i * 512 + o)) * 4 + p]);
}

// conv3_W (64,512,3,3) -> bf16 Wt[o][tap*512+ci]
__global__ void reorder_c3_bf_ker(const float* __restrict__ W, unsigned short* __restrict__ Wt) {
  int t = blockIdx.x * 256 + threadIdx.x;       // 294,912
  if (t >= 64 * 4608) return;
  int o = t / 4608, rem = t - o * 4608, tap = rem >> 9, ci = rem & 511;
  Wt[t] = f2bf(W[((size_t)(o * 512 + ci)) * 9 + tap]);
}

// ------------------------------------------- f32 GEMM NT (qa/ka only, tiny)
__device__ __forceinline__ void fma16(const float4 av, const float4 bv, float acc[4][4]) {
  acc[0][0] += av.x*bv.x; acc[0][1] += av.x*bv.y; acc[0][2] += av.x*bv.z; acc[0][3] += av.x*bv.w;
  acc[1][0] += av.y*bv.x; acc[1][1] += av.y*bv.y; acc[1][2] += av.y*bv.z; acc[1][3] += av.y*bv.w;
  acc[2][0] += av.z*bv.x; acc[2][1] += av.z*bv.y; acc[2][2] += av.z*bv.z; acc[2][3] += av.z*bv.w;
  acc[3][0] += av.w*bv.x; acc[3][1] += av.w*bv.y; acc[3][2] += av.w*bv.z; acc[3][3] += av.w*bv.w;
}
__global__ __launch_bounds__(256) void gemm_nt_f32_ker(
    const float* __restrict__ A, const float* __restrict__ B,
    const float* __restrict__ bias, float* __restrict__ C, int M, int N, int K)
{
  __shared__ float As[16][68];
  __shared__ float Bs[16][68];
  const int tid = threadIdx.x;
  const int tx = tid & 15, ty = tid >> 4;
  const int bm = blockIdx.y * 64, bn = blockIdx.x * 64;
  const int lr = tid >> 2, lk = (tid & 3) << 2;
  const float* Ap = A + (size_t)(bm + lr) * K + lk;
  const float* Bp = B + (size_t)(bn + lr) * K + lk;
  float acc[4][4] = {};
  for (int k0 = 0; k0 < K; k0 += 16) {
    float4 a4 = *(const float4*)(Ap + k0);
    float4 b4 = *(const float4*)(Bp + k0);
    __syncthreads();
    As[lk+0][lr] = a4.x; As[lk+1][lr] = a4.y; As[lk+2][lr] = a4.z; As[lk+3][lr] = a4.w;
    Bs[lk+0][lr] = b4.x; Bs[lk+1][lr] = b4.y; Bs[lk+2][lr] = b4.z; Bs[lk+3][lr] = b4.w;
    __syncthreads();
#pragma unroll
    for (int k = 0; k < 16; ++k) {
      const float4 av = *(const float4*)&As[k][ty << 2];
      const float4 bv = *(const float4*)&Bs[k][tx << 2];
      fma16(av, bv, acc);
    }
  }
#pragma unroll
  for (int i = 0; i < 4; ++i)
#pragma unroll
    for (int j = 0; j < 4; ++j) {
      const int row = bm + (ty << 2) + i, col = bn + (tx << 2) + j;
      C[(size_t)row * N + col] = acc[i][j] + bias[col];
    }
}

// ---------------------- small NN GEMM: Out[ba,i] = sum_c X[ba,c] * W[c,i]
__global__ void nn8_ker(const float* __restrict__ X, const float* __restrict__ W,
                        float* __restrict__ Out)
{
  const int ba = blockIdx.x;                     // 64 rows
  const int i  = threadIdx.x;                    // 512
  __shared__ float xr[512];
  xr[i] = X[(size_t)ba * 512 + i];
  __syncthreads();
  float s = 0.f;
#pragma unroll 4
  for (int c = 0; c < 512; ++c) s += xr[c] * W[(size_t)c * 512 + i];
  Out[(size_t)ba * 512 + i] = s;
}

// consts: cas[ba]=dot(qa[ba],ks_b), cqa[ba]=dot(ka[ba],qa_b)
__global__ void score_const_ker(const float* __restrict__ qa, const float* __restrict__ ka,
                                const float* __restrict__ ks_b, const float* __restrict__ qa_b,
                                float* __restrict__ cas, float* __restrict__ cqa)
{
  const int t = threadIdx.x;                     // 64
  float s1 = 0.f, s2 = 0.f;
  for (int c = 0; c < 512; ++c) {
    s1 += qa[(size_t)t * 512 + c] * ks_b[c];
    s2 += ka[(size_t)t * 512 + c] * qa_b[c];
  }
  cas[t] = s1; cqa[t] = s2;
}

// scores: s_as[b,a,h] = (qk[b,a]·supp[b,h] + cas)/8 ; s_qa[b,h,a] likewise
__global__ void scores_both_ker(const float* __restrict__ qk, const float* __restrict__ kq,
                                const float* __restrict__ supp, const float* __restrict__ query,
                                const float* __restrict__ cas, const float* __restrict__ cqa,
                                float* __restrict__ s_as, float* __restrict__ s_qa)
{
  const int t = blockIdx.x * 256 + threadIdx.x;  // 65536
  const int a = t & 7, h = (t >> 3) & 1023, b = t >> 13;
  const float* qkp = qk + (size_t)(b * 8 + a) * 512;
  const float* sp  = supp + ((size_t)b * 1024 + h) * 512;
  const float* kqp = kq + (size_t)(b * 8 + a) * 512;
  const float* qp  = query + ((size_t)b * 1024 + h) * 512;
  float s1 = 0.f, s2 = 0.f;
  for (int k = 0; k < 512; k += 4) {
    float4 xv = *(const float4*)(qkp + k), yv = *(const float4*)(sp + k);
    s1 += xv.x*yv.x + xv.y*yv.y + xv.z*yv.z + xv.w*yv.w;
    float4 uv = *(const float4*)(kqp + k), wv = *(const float4*)(qp + k);
    s2 += uv.x*wv.x + uv.y*wv.y + uv.z*wv.z + uv.w*wv.w;
  }
  s_as[((size_t)(b * 8 + a)) * 1024 + h] = 0.125f * (s1 + cas[b * 8 + a]);
  s_qa[((size_t)(b * 1024 + h)) * 8 + a] = 0.125f * (s2 + cqa[b * 8 + a]);
}

// ---------------------------------------------- bf16 MFMA GEMM NT (+scatter)
// 2-phase double-buffered pipeline. BM=BN=128, BK=32; 4 waves, 4x4 frags.
// MODE 0: C[row*N+col], z batches via sA/sB/sC.
// MODE 2: z = ConvT parity (dy=z>>1,dx=z&1), B at z*sB, scatter epilogue.
template<int MODE>
__global__ __launch_bounds__(256) void mfma_nt_ker(
    const unsigned short* __restrict__ A, const unsigned short* __restrict__ B,
    const float* __restrict__ bias, unsigned short* __restrict__ C,
    int M, int N, int K, int relu,
    long sA, long sB, long sC,
    int pixShift, int winShift, long outBS)
{
  (void)M;
  __shared__ __align__(16) unsigned short As[2][128 * 32];
  __shared__ __align__(16) unsigned short Bs[2][128 * 32];
  const int tid = threadIdx.x, wave = tid >> 6, lane = tid & 63;
  const int wm = wave >> 1, wn = wave & 1;
  const int bm = blockIdx.y * 128, bn = blockIdx.x * 128;
  const int z = blockIdx.z;
  const unsigned short* Az = A + (MODE == 2 ? 0 : (size_t)z * sA);
  const unsigned short* Bz = B + (size_t)z * sB;

  f32x4 zero4 = {0.f, 0.f, 0.f, 0.f};
  f32x4 acc[4][4];
#pragma unroll
  for (int i = 0; i < 4; ++i)
#pragma unroll
    for (int j = 0; j < 4; ++j) acc[i][j] = zero4;

#define STAGE_NT(buf, kk)                                                     \
  {                                                                           \
    _Pragma("unroll")                                                         \
    for (int q = 0; q < 2; ++q) {                                             \
      int idx = q * 256 + tid;                                                \
      int rr = idx >> 2, s = idx & 3;                                         \
      stage16(Az + (size_t)(bm + rr) * K + (kk) + ((s ^ swz(rr)) << 3),       \
              &As[buf][(q * 256 + wave * 64) * 8]);                           \
    }                                                                         \
    _Pragma("unroll")                                                         \
    for (int q = 0; q < 2; ++q) {                                             \
      int idx = q * 256 + tid;                                                \
      int rr = idx >> 2, s = idx & 3;                                         \
      stage16(Bz + (size_t)(bn + rr) * K + (kk) + ((s ^ swz(rr)) << 3),       \
              &Bs[buf][(q * 256 + wave * 64) * 8]);                           \
    }                                                                         \
  }

  STAGE_NT(0, 0);
  __syncthreads();                                // buf0 ready
  const int nt = K >> 5;
  int cur = 0;
  for (int t = 0; t < nt; ++t) {
    if (t + 1 < nt) STAGE_NT(cur ^ 1, (t + 1) << 5);   // loads fly under MFMA
    short8 af[4], bfr[4];
#pragma unroll
    for (int mt = 0; mt < 4; ++mt) {
      int r = wm * 64 + mt * 16 + (lane & 15);
      int s = (lane >> 4) ^ swz(r);
      af[mt] = *(const short8*)&As[cur][r * 32 + s * 8];
    }
#pragma unroll
    for (int ntt = 0; ntt < 4; ++ntt) {
      int r = wn * 64 + ntt * 16 + (lane & 15);
      int s = (lane >> 4) ^ swz(r);
      bfr[ntt] = *(const short8*)&Bs[cur][r * 32 + s * 8];
    }
#pragma unroll
    for (int mt = 0; mt < 4; ++mt)
#pragma unroll
      for (int ntt = 0; ntt < 4; ++ntt)
        acc[mt][ntt] = __builtin_amdgcn_mfma_f32_16x16x32_bf16(af[mt], bfr[ntt], acc[mt][ntt], 0, 0, 0);
    __syncthreads();                              // drain next-tile loads
    cur ^= 1;
  }
#undef STAGE_NT

  unsigned short* Cz = C + (MODE == 2 ? 0 : (size_t)z * sC);
  const int pdy = (MODE == 2) ? (z >> 1) : 0;
  const int pdx = (MODE == 2) ? (z & 1) : 0;
#pragma unroll
  for (int mt = 0; mt < 4; ++mt)
#pragma unroll
    for (int ntt = 0; ntt < 4; ++ntt)
#pragma unroll
      for (int q = 0; q < 4; ++q) {
        int row = bm + wm * 64 + mt * 16 + ((lane >> 4) << 2) + q;
        int col = bn + wn * 64 + ntt * 16 + (lane & 15);
        float v = acc[mt][ntt][q];
        if (bias) v += bias[col];
        if (relu) v = fmaxf(v, 0.f);
        if (MODE == 0) {
          Cz[(size_t)row * N + col] = f2bf(v);
        } else {
          int bb = row >> pixShift;
          int pix = row & ((1 << pixShift) - 1);
          int y = pix >> winShift, x = pix & ((1 << winShift) - 1);
          int yy = 2 * y + pdy, xx = 2 * x + pdx;
          long o = (long)bb * outBS + ((long)yy * (2 << winShift) + xx) * (long)N + col;
          Cz[o] = f2bf(v);
        }
      }
}

// ----------------------- conv3x3 MFMA (per 2 batches): gathered-A GEMM
// X: x2 [2][128][128][512] bf16; Wt: [64][4608]; Y: [32768][64], relu.
// BM=128 (one pixel row), BN=64, K=4608, 2-phase pipeline, zbuf for pads.
__global__ __launch_bounds__(256) void mfma_conv3_ker(
    const unsigned short* __restrict__ X, const unsigned short* __restrict__ Wt,
    unsigned short* __restrict__ Y, const unsigned short* __restrict__ zbuf)
{
  __shared__ __align__(16) unsigned short As[2][128 * 32];
  __shared__ __align__(16) unsigned short Bs[2][64 * 32];
  const int tid = threadIdx.x, wave = tid >> 6, lane = tid & 63;
  const int wm = wave >> 1, wn = wave & 1;
  const int bm = blockIdx.x * 128;
  const int bb = bm >> 14, y = (bm & 16383) >> 7;

  f32x4 zero4 = {0.f, 0.f, 0.f, 0.f};
  f32x4 acc[4][2];
#pragma unroll
  for (int i = 0; i < 4; ++i) { acc[i][0] = zero4; acc[i][1] = zero4; }

#define STAGE_C3(buf, kk)                                                     \
  {                                                                           \
    const int tap = (kk) >> 9, ci0 = (kk) & 511;                              \
    const int yy = y + tap / 3 - 1;                                           \
    const int xo = tap % 3 - 1;                                               \
    const bool vrow = ((unsigned)yy < 128u);                                  \
    _Pragma("unroll")                                                         \
    for (int q = 0; q < 2; ++q) {                                             \
      int idx = q * 256 + tid;                                                \
      int rr = idx >> 2, s = idx & 3;                                         \
      int xx = rr + xo;                                                       \
      const unsigned short* src = (vrow && (unsigned)xx < 128u)               \
        ? X + ((((size_t)bb * 128 + yy) * 128 + xx) << 9) + ci0 + ((s ^ swz(rr)) << 3) \
        : zbuf + ((idx & 127) << 3);                                          \
      stage16(src, &As[buf][(q * 256 + wave * 64) * 8]);                      \
    }                                                                         \
    {                                                                         \
      int rr = tid >> 2, s = tid & 3;                                         \
      stage16(Wt + (size_t)rr * 4608 + (kk) + ((s ^ swz(rr)) << 3),           \
              &Bs[buf][(wave * 64) * 8]);                                     \
    }                                                                         \
  }

  STAGE_C3(0, 0);
  __syncthreads();
  int cur = 0;
  for (int t = 0; t < 144; ++t) {
    if (t < 143) STAGE_C3(cur ^ 1, (t + 1) << 5);
    short8 af[4], bfr[2];
#pragma unroll
    for (int mt = 0; mt < 4; ++mt) {
      int r = wm * 64 + mt * 16 + (lane & 15);
      int s = (lane >> 4) ^ swz(r);
      af[mt] = *(const short8*)&As[cur][r * 32 + s * 8];
    }
#pragma unroll
    for (int ntt = 0; ntt < 2; ++ntt) {
      int r = wn * 32 + ntt * 16 + (lane & 15);
      int s = (lane >> 4) ^ swz(r);
      bfr[ntt] = *(const short8*)&Bs[cur][r * 32 + s * 8];
    }
#pragma unroll
    for (int mt = 0; mt < 4; ++mt)
#pragma unroll
      for (int ntt = 0; ntt < 2; ++ntt)
        acc[mt][ntt] = __builtin_amdgcn_mfma_f32_16x16x32_bf16(af[mt], bfr[ntt], acc[mt][ntt], 0, 0, 0);
    __syncthreads();
    cur ^= 1;
  }
#undef STAGE_C3

#pragma unroll
  for (int mt = 0; mt < 4; ++mt)
#pragma unroll
    for (int ntt = 0; ntt < 2; ++ntt)
#pragma unroll
      for (int q = 0; q < 4; ++q) {
        int row = bm + wm * 64 + mt * 16 + ((lane >> 4) << 2) + q;
        int col = wn * 32 + ntt * 16 + (lane & 15);
        Y[(size_t)row * 64 + col] = f2bf(fmaxf(acc[mt][ntt][q], 0.f));
      }
}

// ------------------------------------------------ batched bf16 transpose
__global__ void transpose_bf_ker(const unsigned short* __restrict__ src,
                                 unsigned short* __restrict__ dst, int R, int C)
{
  __shared__ unsigned short tile[32][33];
  const size_t zo = (size_t)blockIdx.z * R * C;
  const int r0 = blockIdx.y * 32, c0 = blockIdx.x * 32;
  const int tx = threadIdx.x & 31, ty = threadIdx.x >> 5;   // 32 x 8
  for (int i = ty; i < 32; i += 8)
    tile[i][tx] = src[zo + (size_t)(r0 + i) * C + c0 + tx];
  __syncthreads();
  for (int i = ty; i < 32; i += 8)
    dst[zo + (size_t)(c0 + i) * R + r0 + tx] = tile[tx][i];
}

// ------------------------------------------------ argmax / softmax
__global__ void argmax_ker(const float* __restrict__ s_as, const float* __restrict__ s_qa,
                           int* __restrict__ a_idx, int* __restrict__ q_idx)
{
  const int t = blockIdx.x * 256 + threadIdx.x;
  if (t >= 8192) return;
  const int b = t >> 10, h = t & 1023;
  {
    const float* p = s_as + (size_t)b * 8192 + h;
    float best = p[0]; int bi = 0;
#pragma unroll
    for (int a = 1; a < 8; ++a) { float v = p[(size_t)a * 1024]; if (v > best) { best = v; bi = a; } }
    a_idx[t] = bi;
  }
  {
    const float* p = s_qa + (size_t)t * 8;
    float best = p[0]; int bi = 0;
#pragma unroll
    for (int a = 1; a < 8; ++a) { float v = p[a]; if (v > best) { best = v; bi = a; } }
    q_idx[t] = bi;
  }
}

__global__ __launch_bounds__(1024) void softmax_ker(
    const float* __restrict__ s_as, const float* __restrict__ s_qa,
    const int* __restrict__ a_idx, const int* __restrict__ q_idx,
    unsigned short* __restrict__ Out)
{
  const int bh = blockIdx.x;                      // b*1024 + h
  const int b = bh >> 10, h = bh & 1023;
  const int j = threadIdx.x;
  __shared__ float red[16];
  __shared__ float sval;
  float u[8];
#pragma unroll
  for (int a = 0; a < 8; ++a) u[a] = s_as[((size_t)(b * 8 + a)) * 1024 + h];
  const int ai = a_idx[bh];
  const float* qrow = s_qa + ((size_t)(b * 1024 + j)) * 8;
  float m = 0.f;
#pragma unroll
  for (int a = 0; a < 8; ++a) m += u[a] * qrow[a];
  if (q_idx[b * 1024 + j] != ai) m -= 1e6f;
  const int lane = j & 63, wid = j >> 6;
  float mx = m;
  for (int off = 32; off; off >>= 1) mx = fmaxf(mx, __shfl_down(mx, off));
  if (lane == 0) red[wid] = mx;
  __syncthreads();
  if (j == 0) { float v = red[0]; for (int i = 1; i < 16; ++i) v = fmaxf(v, red[i]); sval = v; }
  __syncthreads();
  const float MX = sval;
  const float p = __expf(m - MX);
  float sm = p;
  for (int off = 32; off; off >>= 1) sm += __shfl_down(sm, off);
  if (lane == 0) red[wid] = sm;
  __syncthreads();
  if (j == 0) { float v = 0.f; for (int i = 0; i < 16; ++i) v += red[i]; sval = v; }
  __syncthreads();
  Out[(size_t)bh * 1024 + j] = f2bf(p / sval);
}

// -------- conv1 3x3 (Cin=64, Cout=3), channel-major bf16 input, f32 NCHW out
__global__ void conv1_ker(const unsigned short* __restrict__ X3T,
                          const float* __restrict__ Wsrc, float* __restrict__ Out)
{
  __shared__ float Wl[9 * 64 * 3];                 // [tap][ci][o]
  for (int i = threadIdx.x; i < 1728; i += 256) {
    int o = i / 576, rem = i - o * 576, ci = rem / 9, tap = rem - ci * 9;
    Wl[(tap * 64 + ci) * 3 + o] = Wsrc[((size_t)(o * 64 + ci)) * 9 + tap];
  }
  __syncthreads();
  const int pix2 = blockIdx.x * 256 + threadIdx.x; // 0..32767
  const int bl = pix2 >> 14, pix = pix2 & 16383, y = pix >> 7, x = pix & 127;
  float acc0 = 0.f, acc1 = 0.f, acc2 = 0.f;
#pragma unroll
  for (int tap = 0; tap < 9; ++tap) {
    const int yy = y + tap / 3 - 1, xx = x + tap % 3 - 1;
    if ((unsigned)yy >= 128u || (unsigned)xx >= 128u) continue;
    const size_t p = (size_t)bl * 16384 + (size_t)yy * 128 + xx;
    const float* w = &Wl[tap * 192];
#pragma unroll
    for (int ci = 0; ci < 64; ++ci) {
      float v = bf2f(X3T[(size_t)ci * 32768 + p]);
      acc0 += v * w[ci * 3 + 0];
      acc1 += v * w[ci * 3 + 1];
      acc2 += v * w[ci * 3 + 2];
    }
  }
  const size_t base = (size_t)bl * 49152 + (size_t)y * 128 + x;
  Out[base]         = acc0;
  Out[base + 16384] = acc1;
  Out[base + 32768] = acc2;
}

// ================================================================ launch
extern "C" void kernel_launch(void* const* d_in, const int* in_sizes, int n_in,
                              void* d_out, int out_size, void* d_ws, size_t ws_size,
                              hipStream_t stream)
{
  (void)in_sizes; (void)n_in; (void)out_size; (void)ws_size;
  const float* tok    = (const float*)d_in[0];
  const float* supp   = (const float*)d_in[1];
  const float* query  = (const float*)d_in[2];
  const float* qa_W   = (const float*)d_in[3];  const float* qa_b  = (const float*)d_in[4];
  const float* ks_W   = (const float*)d_in[5];  const float* ks_b  = (const float*)d_in[6];
  const float* ka_W   = (const float*)d_in[7];  const float* ka_b  = (const float*)d_in[8];
  const float* vs_W   = (const float*)d_in[9];  const float* vs_b  = (const float*)d_in[10];
  const float* ffn_W1 = (const float*)d_in[11]; const float* ffn_b1= (const float*)d_in[12];
  const float* ffn_W2 = (const float*)d_in[13]; const float* ffn_b2= (const float*)d_in[14];
  const float* up0_W  = (const float*)d_in[15]; const float* up0_b = (const float*)d_in[16];
  const float* up1_W  = (const float*)d_in[17]; const float* up1_b = (const float*)d_in[18];
  const float* c3_W   = (const float*)d_in[19]; const float* c1_W  = (const float*)d_in[20];
  float* out = (float*)d_out;

  float* F = (float*)d_ws;
  // persistent region
  unsigned short* vsWb   = (unsigned short*)(F + 0);
  unsigned short* ffnW1b = (unsigned short*)(F + 131072);
  unsigned short* ffnW2b = (unsigned short*)(F + 655360);
  unsigned short* up0t   = (unsigned short*)(F + 1179648);
  unsigned short* up1t   = (unsigned short*)(F + 1703936);
  unsigned short* c3t    = (unsigned short*)(F + 2228224);
  float* qa    = F + 2375680;
  float* ka    = F + 2408448;
  float* s_as  = F + 2441216;
  float* s_qa  = F + 2506752;
  int*   a_idx = (int*)(F + 2572288);
  int*   q_idx = (int*)(F + 2580480);
  unsigned short* zbuf = (unsigned short*)(F + 2588672);   // 4 KB, memset 0
  // slots
  unsigned short* sqsT  = (unsigned short*)(F + 2589696);      // S1
  unsigned short* dec   = (unsigned short*)(F + 2589696);      // S1
  unsigned short* x3    = (unsigned short*)(F + 2589696);      // S1 (pair)
  unsigned short* x3T   = (unsigned short*)(F + 2589696 + 1048576);
  float* qk             = F + 6784000;                         // S2 head (dead pre-softmax)
  float* kq             = F + 6784000 + 32768;
  float* cas            = F + 6784000 + 65536;
  float* cqa            = F + 6784000 + 65600;
  unsigned short* sqs   = (unsigned short*)(F + 6784000);      // S2
  unsigned short* x2    = (unsigned short*)(F + 6784000);      // S2..S4 contiguous
  unsigned short* suppb = (unsigned short*)(F + 10978304);     // S3
  unsigned short* vsT   = (unsigned short*)(F + 10978304);     // S3
  unsigned short* t0    = (unsigned short*)(F + 10978304);     // S3
  unsigned short* vsb   = (unsigned short*)(F + 13075456);     // S4
  unsigned short* attn  = (unsigned short*)(F + 13075456);     // S4
  unsigned short* h1    = (unsigned short*)(F + 15172608);     // S5
  unsigned short* x1    = (unsigned short*)(F + 15172608);     // S5

  hipMemsetAsync(zbuf, 0, 4096, stream);

  // converts / reorders
  cvt_bf_ker<<<4096, 256, 0, stream>>>(supp,   suppb,  1048576);
  cvt_bf_ker<<<256,  256, 0, stream>>>(vs_W,   vsWb,   65536);
  cvt_bf_ker<<<1024, 256, 0, stream>>>(ffn_W1, ffnW1b, 262144);
  cvt_bf_ker<<<1024, 256, 0, stream>>>(ffn_W2, ffnW2b, 262144);
  reorder_up_bf_ker<<<4096, 256, 0, stream>>>(up0_W, up0t);
  reorder_up_bf_ker<<<4096, 256, 0, stream>>>(up1_W, up1t);
  reorder_c3_bf_ker<<<1152, 256, 0, stream>>>(c3_W, c3t);

  // f32 score path (tiny): qa, ka, then qk = qa@ks_W, kq = ka@qa_W
  gemm_nt_f32_ker<<<dim3(8, 1), 256, 0, stream>>>(tok, qa_W, qa_b, qa, 64, 512, 512);
  gemm_nt_f32_ker<<<dim3(8, 1), 256, 0, stream>>>(tok, ka_W, ka_b, ka, 64, 512, 512);
  nn8_ker<<<64, 512, 0, stream>>>(qa, ks_W, qk);
  nn8_ker<<<64, 512, 0, stream>>>(ka, qa_W, kq);
  score_const_ker<<<1, 64, 0, stream>>>(qa, ka, ks_b, qa_b, cas, cqa);
  scores_both_ker<<<256, 256, 0, stream>>>(qk, kq, supp, query, cas, cqa, s_as, s_qa);

  // vs projection (bf16 MFMA)
  mfma_nt_ker<0><<<dim3(4, 64, 1), 256, 0, stream>>>(suppb, vsWb, vs_b, vsb,
      8192, 512, 512, 0, 0, 0, 0, 0, 0, 0);

  argmax_ker<<<32, 256, 0, stream>>>(s_as, s_qa, a_idx, q_idx);
  softmax_ker<<<8192, 1024, 0, stream>>>(s_as, s_qa, a_idx, q_idx, sqs);

  // transposes for PV operands
  transpose_bf_ker<<<dim3(32, 32, 8), 256, 0, stream>>>(sqs, sqsT, 1024, 1024); // S2->S1
  transpose_bf_ker<<<dim3(16, 32, 8), 256, 0, stream>>>(vsb, vsT, 1024, 512);   // S4->S3

  // attn[b,i,c] = sum_h P[b,h,i] * vs[b,h,c]  (batched MFMA)
  mfma_nt_ker<0><<<dim3(4, 8, 8), 256, 0, stream>>>(sqsT, vsT, nullptr, attn,
      1024, 512, 1024, 0, 1024L*1024, 512L*1024, 1024L*512, 0, 0, 0);

  // FFN
  mfma_nt_ker<0><<<dim3(16, 64, 1), 256, 0, stream>>>(attn, ffnW1b, ffn_b1, h1,
      8192, 2048, 512, 1, 0, 0, 0, 0, 0, 0);
  mfma_nt_ker<0><<<dim3(4, 64, 1), 256, 0, stream>>>(h1, ffnW2b, ffn_b2, dec,
      8192, 512, 2048, 0, 0, 0, 0, 0, 0, 0);

  // dec raw-reinterpret (b,512,32,32) -> NHWC t0 [b][1024][512]
  transpose_bf_ker<<<dim3(32, 16, 8), 256, 0, stream>>>(dec, t0, 512, 1024);    // S1->S3

  // up0: all 4 parities in one launch (z = parity), scatter to x1 [8][64][64][512]
  mfma_nt_ker<2><<<dim3(4, 64, 4), 256, 0, stream>>>(t0, up0t, up0_b, x1,
      8192, 512, 512, 0, 0, 262144, 0, 10, 5, 2097152L);

  // per 2-batch pair: up1 -> x2, conv3 -> x3, transpose, conv1 -> out
  for (int pair = 0; pair < 4; ++pair) {
    const unsigned short* x1p = x1 + (size_t)pair * 4194304;
    mfma_nt_ker<2><<<dim3(4, 64, 4), 256, 0, stream>>>(x1p, up1t, up1_b, x2,
        8192, 512, 512, 0, 0, 262144, 0, 12, 6, 8388608L);
    mfma_conv3_ker<<<256, 256, 0, stream>>>(x2, c3t, x3, zbuf);
    transpose_bf_ker<<<dim3(2, 1024, 1), 256, 0, stream>>>(x3, x3T, 32768, 64);
    conv1_ker<<<128, 256, 0, stream>>>(x3T, c1_W, out + (size_t)pair * 98304);
  }
}

// Round 10
// 1109.417 us; speedup vs baseline: 5.4651x; 1.1205x over previous
//
#include <hip/hip_runtime.h>

// AgentMatchingDecoder on MI355X — round 10: round-8 fusion + arena-overlap FIX.
// Round-9 failure root-caused: bias_tap was placed at F+10978304+131072 floats,
// i.e. INSIDE Weff (which spans 262144 floats) -> bias_tap_ker clobbered
// Weff[cls=2][o=0][0..1152) -> 1.37e-3 absmax. Fix: bias_tap at +262144.
// Fusion: out3 = conv3x3(convT2x2(x1)) == per-parity-class 2x2-neighborhood
// GEMM on x1 with contracted Weff[cls][o][rc,i], K=2048. 146 GF -> 34.4 GF.

using short8 = __attribute__((ext_vector_type(8))) short;   // 8 bf16 (4 VGPR)
using f32x4  = __attribute__((ext_vector_type(4))) float;   // MFMA acc

__device__ __forceinline__ unsigned short f2bf(float f) {
  unsigned int u = __float_as_uint(f);
  return (unsigned short)((u + 0x7FFFu + ((u >> 16) & 1u)) >> 16);
}
__device__ __forceinline__ float bf2f(unsigned short h) {
  return __uint_as_float(((unsigned int)h) << 16);
}
__device__ __forceinline__ void stage16(const unsigned short* g, unsigned short* l) {
  __builtin_amdgcn_global_load_lds(
      (const __attribute__((address_space(1))) unsigned int*)g,
      (__attribute__((address_space(3))) unsigned int*)l, 16, 0, 0);
}
// LDS slot swizzle: involution over the 4 16-byte slots of a 64B tile row.
__device__ __forceinline__ int swz(int r) { return (r & 3) ^ ((r >> 2) & 3); }

// ------------------------------------------------------------ converts
__global__ void cvt_bf_ker(const float* __restrict__ in, unsigned short* __restrict__ out, int n4) {
  int i = blockIdx.x * 256 + threadIdx.x;
  if (i >= n4) return;
  float4 v = ((const float4*)in)[i];
  unsigned int lo = (unsigned int)f2bf(v.x) | ((unsigned int)f2bf(v.y) << 16);
  unsigned int hi = (unsigned int)f2bf(v.z) | ((unsigned int)f2bf(v.w) << 16);
  ((uint2*)out)[i] = make_uint2(lo, hi);
}

// up*_W (in=512,out=512,2,2) -> bf16 Wt[p][o][i], p = dy*2+dx
__global__ void reorder_up_bf_ker(const float* __restrict__ W, unsigned short* __restrict__ Wt) {
  int t = blockIdx.x * 256 + threadIdx.x;       // 1,048,576
  int i = t & 511, o = (t >> 9) & 511, p = t >> 18;
  Wt[t] = f2bf(W[((size_t)(i * 512 + o)) * 4 + p]);
}

// conv3_W (64,512,3,3) -> bf16 Wt[o][tap*512+ci]
__global__ void reorder_c3_bf_ker(const float* __restrict__ W, unsigned short* __restrict__ Wt) {
  int t = blockIdx.x * 256 + threadIdx.x;       // 294,912
  if (t >= 64 * 4608) return;
  int o = t / 4608, rem = t - o * 4608, tap = rem >> 9, ci = rem & 511;
  Wt[t] = f2bf(W[((size_t)(o * 512 + ci)) * 9 + tap]);
}

// --------- Weff[cls][o][(r*2+c)*512+i] = sum_{taps->(r,c)} sum_ci c3*W1
// cls = py*2+px. Tap (ky,kx): ur = py+ky-1; rl = (ur>>1)+1-py; pu = ur&1.
__global__ void weff_ker(const unsigned short* __restrict__ c3t,
                         const unsigned short* __restrict__ up1t,
                         unsigned short* __restrict__ Weff)
{
  const int itile = blockIdx.x;                  // 8 tiles of 64 i
  const int q = blockIdx.y;                      // 16 = cls*4 + slab
  const int cls = q >> 2, slab = q & 3;
  const int py = cls >> 1, px = cls & 1;
  const int rs = slab >> 1, cs = slab & 1;
  const int o = threadIdx.x & 63;
  const int i0 = itile * 64 + (threadIdx.x >> 6) * 16;
  float acc[16] = {};
  for (int ky = 0; ky < 3; ++ky) {
    int ur = py + ky - 1;
    if (((ur >> 1) + 1 - py) != rs) continue;
    int pu = ur & 1;
    for (int kx = 0; kx < 3; ++kx) {
      int vr = px + kx - 1;
      if (((vr >> 1) + 1 - px) != cs) continue;
      int pv = vr & 1;
      const unsigned short* wtap = c3t + (size_t)o * 4608 + (ky * 3 + kx) * 512;
      const unsigned short* w1 = up1t + (size_t)(pu * 2 + pv) * 262144 + i0;
      for (int ci = 0; ci < 512; ++ci) {
        float a = bf2f(wtap[ci]);
        const unsigned short* row = w1 + (size_t)ci * 512;
        short8 v0 = *(const short8*)(row);
        short8 v1 = *(const short8*)(row + 8);
#pragma unroll
        for (int k = 0; k < 8; ++k) acc[k]     += a * bf2f((unsigned short)v0[k]);
#pragma unroll
        for (int k = 0; k < 8; ++k) acc[k + 8] += a * bf2f((unsigned short)v1[k]);
      }
    }
  }
  unsigned short* dst = Weff + (size_t)cls * 131072 + (size_t)o * 2048 + slab * 512 + i0;
#pragma unroll
  for (int k = 0; k < 16; ++k) dst[k] = f2bf(acc[k]);
}

// bias_tap[tap][o] = sum_ci c3_W[o][ci][tap] * up1_b[ci]   (f32 inputs)
__global__ void bias_tap_ker(const float* __restrict__ c3W, const float* __restrict__ up1b,
                             float* __restrict__ bias_tap)
{
  for (int idx = threadIdx.x; idx < 576; idx += 256) {
    int tap = idx >> 6, o = idx & 63;
    float s = 0.f;
    for (int ci = 0; ci < 512; ++ci)
      s += c3W[(size_t)(o * 512 + ci) * 9 + tap] * up1b[ci];
    bias_tap[tap * 64 + o] = s;
  }
}

// ------------------------------------------- f32 GEMM NT (qa/ka only, tiny)
__device__ __forceinline__ void fma16(const float4 av, const float4 bv, float acc[4][4]) {
  acc[0][0] += av.x*bv.x; acc[0][1] += av.x*bv.y; acc[0][2] += av.x*bv.z; acc[0][3] += av.x*bv.w;
  acc[1][0] += av.y*bv.x; acc[1][1] += av.y*bv.y; acc[1][2] += av.y*bv.z; acc[1][3] += av.y*bv.w;
  acc[2][0] += av.z*bv.x; acc[2][1] += av.z*bv.y; acc[2][2] += av.z*bv.z; acc[2][3] += av.z*bv.w;
  acc[3][0] += av.w*bv.x; acc[3][1] += av.w*bv.y; acc[3][2] += av.w*bv.z; acc[3][3] += av.w*bv.w;
}
__global__ __launch_bounds__(256) void gemm_nt_f32_ker(
    const float* __restrict__ A, const float* __restrict__ B,
    const float* __restrict__ bias, float* __restrict__ C, int M, int N, int K)
{
  __shared__ float As[16][68];
  __shared__ float Bs[16][68];
  const int tid = threadIdx.x;
  const int tx = tid & 15, ty = tid >> 4;
  const int bm = blockIdx.y * 64, bn = blockIdx.x * 64;
  const int lr = tid >> 2, lk = (tid & 3) << 2;
  const float* Ap = A + (size_t)(bm + lr) * K + lk;
  const float* Bp = B + (size_t)(bn + lr) * K + lk;
  float acc[4][4] = {};
  for (int k0 = 0; k0 < K; k0 += 16) {
    float4 a4 = *(const float4*)(Ap + k0);
    float4 b4 = *(const float4*)(Bp + k0);
    __syncthreads();
    As[lk+0][lr] = a4.x; As[lk+1][lr] = a4.y; As[lk+2][lr] = a4.z; As[lk+3][lr] = a4.w;
    Bs[lk+0][lr] = b4.x; Bs[lk+1][lr] = b4.y; Bs[lk+2][lr] = b4.z; Bs[lk+3][lr] = b4.w;
    __syncthreads();
#pragma unroll
    for (int k = 0; k < 16; ++k) {
      const float4 av = *(const float4*)&As[k][ty << 2];
      const float4 bv = *(const float4*)&Bs[k][tx << 2];
      fma16(av, bv, acc);
    }
  }
#pragma unroll
  for (int i = 0; i < 4; ++i)
#pragma unroll
    for (int j = 0; j < 4; ++j) {
      const int row = bm + (ty << 2) + i, col = bn + (tx << 2) + j;
      C[(size_t)row * N + col] = acc[i][j] + bias[col];
    }
}

// ---------------------- small NN GEMM: Out[ba,i] = sum_c X[ba,c] * W[c,i]
__global__ void nn8_ker(const float* __restrict__ X, const float* __restrict__ W,
                        float* __restrict__ Out)
{
  const int ba = blockIdx.x;                     // 64 rows
  const int i  = threadIdx.x;                    // 512
  __shared__ float xr[512];
  xr[i] = X[(size_t)ba * 512 + i];
  __syncthreads();
  float s = 0.f;
#pragma unroll 4
  for (int c = 0; c < 512; ++c) s += xr[c] * W[(size_t)c * 512 + i];
  Out[(size_t)ba * 512 + i] = s;
}

// consts: cas[ba]=dot(qa[ba],ks_b), cqa[ba]=dot(ka[ba],qa_b)
__global__ void score_const_ker(const float* __restrict__ qa, const float* __restrict__ ka,
                                const float* __restrict__ ks_b, const float* __restrict__ qa_b,
                                float* __restrict__ cas, float* __restrict__ cqa)
{
  const int t = threadIdx.x;                     // 64
  float s1 = 0.f, s2 = 0.f;
  for (int c = 0; c < 512; ++c) {
    s1 += qa[(size_t)t * 512 + c] * ks_b[c];
    s2 += ka[(size_t)t * 512 + c] * qa_b[c];
  }
  cas[t] = s1; cqa[t] = s2;
}

// scores: s_as[b,a,h] = (qk[b,a]·supp[b,h] + cas)/8 ; s_qa[b,h,a] likewise
__global__ void scores_both_ker(const float* __restrict__ qk, const float* __restrict__ kq,
                                const float* __restrict__ supp, const float* __restrict__ query,
                                const float* __restrict__ cas, const float* __restrict__ cqa,
                                float* __restrict__ s_as, float* __restrict__ s_qa)
{
  const int t = blockIdx.x * 256 + threadIdx.x;  // 65536
  const int a = t & 7, h = (t >> 3) & 1023, b = t >> 13;
  const float* qkp = qk + (size_t)(b * 8 + a) * 512;
  const float* sp  = supp + ((size_t)b * 1024 + h) * 512;
  const float* kqp = kq + (size_t)(b * 8 + a) * 512;
  const float* qp  = query + ((size_t)b * 1024 + h) * 512;
  float s1 = 0.f, s2 = 0.f;
  for (int k = 0; k < 512; k += 4) {
    float4 xv = *(const float4*)(qkp + k), yv = *(const float4*)(sp + k);
    s1 += xv.x*yv.x + xv.y*yv.y + xv.z*yv.z + xv.w*yv.w;
    float4 uv = *(const float4*)(kqp + k), wv = *(const float4*)(qp + k);
    s2 += uv.x*wv.x + uv.y*wv.y + uv.z*wv.z + uv.w*wv.w;
  }
  s_as[((size_t)(b * 8 + a)) * 1024 + h] = 0.125f * (s1 + cas[b * 8 + a]);
  s_qa[((size_t)(b * 1024 + h)) * 8 + a] = 0.125f * (s2 + cqa[b * 8 + a]);
}

// ---------------------------------------------- bf16 MFMA GEMM NT (+scatter)
// 2-phase double-buffered pipeline. BM=BN=128, BK=32; 4 waves, 4x4 frags.
// MODE 0: C[row*N+col], z batches via sA/sB/sC.
// MODE 2: z = ConvT parity (dy=z>>1,dx=z&1), B at z*sB, scatter epilogue.
template<int MODE>
__global__ __launch_bounds__(256) void mfma_nt_ker(
    const unsigned short* __restrict__ A, const unsigned short* __restrict__ B,
    const float* __restrict__ bias, unsigned short* __restrict__ C,
    int M, int N, int K, int relu,
    long sA, long sB, long sC,
    int pixShift, int winShift, long outBS)
{
  (void)M;
  __shared__ __align__(16) unsigned short As[2][128 * 32];
  __shared__ __align__(16) unsigned short Bs[2][128 * 32];
  const int tid = threadIdx.x, wave = tid >> 6, lane = tid & 63;
  const int wm = wave >> 1, wn = wave & 1;
  const int bm = blockIdx.y * 128, bn = blockIdx.x * 128;
  const int z = blockIdx.z;
  const unsigned short* Az = A + (MODE == 2 ? 0 : (size_t)z * sA);
  const unsigned short* Bz = B + (size_t)z * sB;

  f32x4 zero4 = {0.f, 0.f, 0.f, 0.f};
  f32x4 acc[4][4];
#pragma unroll
  for (int i = 0; i < 4; ++i)
#pragma unroll
    for (int j = 0; j < 4; ++j) acc[i][j] = zero4;

#define STAGE_NT(buf, kk)                                                     \
  {                                                                           \
    _Pragma("unroll")                                                         \
    for (int q = 0; q < 2; ++q) {                                             \
      int idx = q * 256 + tid;                                                \
      int rr = idx >> 2, s = idx & 3;                                         \
      stage16(Az + (size_t)(bm + rr) * K + (kk) + ((s ^ swz(rr)) << 3),       \
              &As[buf][(q * 256 + wave * 64) * 8]);                           \
    }                                                                         \
    _Pragma("unroll")                                                         \
    for (int q = 0; q < 2; ++q) {                                             \
      int idx = q * 256 + tid;                                                \
      int rr = idx >> 2, s = idx & 3;                                         \
      stage16(Bz + (size_t)(bn + rr) * K + (kk) + ((s ^ swz(rr)) << 3),       \
              &Bs[buf][(q * 256 + wave * 64) * 8]);                           \
    }                                                                         \
  }

  STAGE_NT(0, 0);
  __syncthreads();                                // buf0 ready
  const int nt = K >> 5;
  int cur = 0;
  for (int t = 0; t < nt; ++t) {
    if (t + 1 < nt) STAGE_NT(cur ^ 1, (t + 1) << 5);   // loads fly under MFMA
    short8 af[4], bfr[4];
#pragma unroll
    for (int mt = 0; mt < 4; ++mt) {
      int r = wm * 64 + mt * 16 + (lane & 15);
      int s = (lane >> 4) ^ swz(r);
      af[mt] = *(const short8*)&As[cur][r * 32 + s * 8];
    }
#pragma unroll
    for (int ntt = 0; ntt < 4; ++ntt) {
      int r = wn * 64 + ntt * 16 + (lane & 15);
      int s = (lane >> 4) ^ swz(r);
      bfr[ntt] = *(const short8*)&Bs[cur][r * 32 + s * 8];
    }
#pragma unroll
    for (int mt = 0; mt < 4; ++mt)
#pragma unroll
      for (int ntt = 0; ntt < 4; ++ntt)
        acc[mt][ntt] = __builtin_amdgcn_mfma_f32_16x16x32_bf16(af[mt], bfr[ntt], acc[mt][ntt], 0, 0, 0);
    __syncthreads();                              // drain next-tile loads
    cur ^= 1;
  }
#undef STAGE_NT

  unsigned short* Cz = C + (MODE == 2 ? 0 : (size_t)z * sC);
  const int pdy = (MODE == 2) ? (z >> 1) : 0;
  const int pdx = (MODE == 2) ? (z & 1) : 0;
#pragma unroll
  for (int mt = 0; mt < 4; ++mt)
#pragma unroll
    for (int ntt = 0; ntt < 4; ++ntt)
#pragma unroll
      for (int q = 0; q < 4; ++q) {
        int row = bm + wm * 64 + mt * 16 + ((lane >> 4) << 2) + q;
        int col = bn + wn * 64 + ntt * 16 + (lane & 15);
        float v = acc[mt][ntt][q];
        if (bias) v += bias[col];
        if (relu) v = fmaxf(v, 0.f);
        if (MODE == 0) {
          Cz[(size_t)row * N + col] = f2bf(v);
        } else {
          int bb = row >> pixShift;
          int pix = row & ((1 << pixShift) - 1);
          int y = pix >> winShift, x = pix & ((1 << winShift) - 1);
          int yy = 2 * y + pdy, xx = 2 * x + pdx;
          long o = (long)bb * outBS + ((long)yy * (2 << winShift) + xx) * (long)N + col;
          Cz[o] = f2bf(v);
        }
      }
}

// --------------- FUSED up1+conv3: per parity class, 2x2-neighborhood GEMM
// x1: [8][64][64][512] bf16; Weff: [4][64][2048] bf16; x3: [8*16384][64] bf16
// grid (32 m-blocks, 4 cls, 8 b); BM=128 px (2 Yc rows x 64 Xc), BN=64, K=2048.
__global__ __launch_bounds__(256) void mfma_upc3_ker(
    const unsigned short* __restrict__ x1, const unsigned short* __restrict__ Weff,
    const float* __restrict__ bias_tap, unsigned short* __restrict__ x3,
    const unsigned short* __restrict__ zbuf)
{
  __shared__ __align__(16) unsigned short As[2][128 * 32];
  __shared__ __align__(16) unsigned short Bs[2][64 * 32];
  __shared__ float btap[576];
  const int tid = threadIdx.x, wave = tid >> 6, lane = tid & 63;
  const int wm = wave >> 1, wn = wave & 1;
  const int mb = blockIdx.x;                     // 0..31
  const int cls = blockIdx.y;                    // 0..3
  const int b = blockIdx.z;                      // 0..7
  const int py = cls >> 1, px = cls & 1;
  for (int i = tid; i < 576; i += 256) btap[i] = bias_tap[i];
  const unsigned short* x1b = x1 + ((size_t)b << 21);       // b*4096*512
  const unsigned short* Wc = Weff + (size_t)cls * 131072;

  f32x4 zero4 = {0.f, 0.f, 0.f, 0.f};
  f32x4 acc[4][2];
#pragma unroll
  for (int i = 0; i < 4; ++i) { acc[i][0] = zero4; acc[i][1] = zero4; }

#define STAGE_UC(buf, kk)                                                     \
  {                                                                           \
    const int slab = (kk) >> 9, i0 = (kk) & 511;                              \
    const int rl = slab >> 1, cl = slab & 1;                                  \
    _Pragma("unroll")                                                         \
    for (int q = 0; q < 2; ++q) {                                             \
      int idx = q * 256 + tid;                                                \
      int rr = idx >> 2, s = idx & 3;                                         \
      int Yc = mb * 2 + (rr >> 6), Xc = rr & 63;                              \
      int yr = Yc + rl + py - 1, xc = Xc + cl + px - 1;                       \
      const unsigned short* src = ((unsigned)yr < 64u && (unsigned)xc < 64u)  \
        ? x1b + (((size_t)yr * 64 + xc) << 9) + i0 + ((s ^ swz(rr)) << 3)     \
        : zbuf + ((idx & 127) << 3);                                          \
      stage16(src, &As[buf][(q * 256 + wave * 64) * 8]);                      \
    }                                                                         \
    {                                                                         \
      int rr = tid >> 2, s = tid & 3;                                         \
      stage16(Wc + (size_t)rr * 2048 + (kk) + ((s ^ swz(rr)) << 3),           \
              &Bs[buf][(wave * 64) * 8]);                                     \
    }                                                                         \
  }

  STAGE_UC(0, 0);
  __syncthreads();
  int cur = 0;
  for (int t = 0; t < 64; ++t) {                 // K = 2048 / 32
    if (t < 63) STAGE_UC(cur ^ 1, (t + 1) << 5);
    short8 af[4], bfr[2];
#pragma unroll
    for (int mt = 0; mt < 4; ++mt) {
      int r = wm * 64 + mt * 16 + (lane & 15);
      int s = (lane >> 4) ^ swz(r);
      af[mt] = *(const short8*)&As[cur][r * 32 + s * 8];
    }
#pragma unroll
    for (int ntt = 0; ntt < 2; ++ntt) {
      int r = wn * 32 + ntt * 16 + (lane & 15);
      int s = (lane >> 4) ^ swz(r);
      bfr[ntt] = *(const short8*)&Bs[cur][r * 32 + s * 8];
    }
#pragma unroll
    for (int mt = 0; mt < 4; ++mt)
#pragma unroll
      for (int ntt = 0; ntt < 2; ++ntt)
        acc[mt][ntt] = __builtin_amdgcn_mfma_f32_16x16x32_bf16(af[mt], bfr[ntt], acc[mt][ntt], 0, 0, 0);
    __syncthreads();
    cur ^= 1;
  }
#undef STAGE_UC

#pragma unroll
  for (int mt = 0; mt < 4; ++mt)
#pragma unroll
    for (int ntt = 0; ntt < 2; ++ntt)
#pragma unroll
      for (int q = 0; q < 4; ++q) {
        int m = wm * 64 + mt * 16 + ((lane >> 4) << 2) + q;
        int o = wn * 32 + ntt * 16 + (lane & 15);
        int Yc = mb * 2 + (m >> 6), Xc = m & 63;
        int Y = 2 * Yc + py, X = 2 * Xc + px;
        float bsum = 0.f;
#pragma unroll
        for (int ky = 0; ky < 3; ++ky) {
          if ((unsigned)(Y + ky - 1) >= 128u) continue;
#pragma unroll
          for (int kx = 0; kx < 3; ++kx)
            if ((unsigned)(X + kx - 1) < 128u) bsum += btap[(ky * 3 + kx) * 64 + o];
        }
        float v = fmaxf(acc[mt][ntt][q] + bsum, 0.f);
        x3[((size_t)b * 16384 + (size_t)Y * 128 + X) * 64 + o] = f2bf(v);
      }
}

// ------------------------------------------------ batched bf16 transpose
__global__ void transpose_bf_ker(const unsigned short* __restrict__ src,
                                 unsigned short* __restrict__ dst, int R, int C)
{
  __shared__ unsigned short tile[32][33];
  const size_t zo = (size_t)blockIdx.z * R * C;
  const int r0 = blockIdx.y * 32, c0 = blockIdx.x * 32;
  const int tx = threadIdx.x & 31, ty = threadIdx.x >> 5;   // 32 x 8
  for (int i = ty; i < 32; i += 8)
    tile[i][tx] = src[zo + (size_t)(r0 + i) * C + c0 + tx];
  __syncthreads();
  for (int i = ty; i < 32; i += 8)
    dst[zo + (size_t)(c0 + i) * R + r0 + tx] = tile[tx][i];
}

// ------------------------------------------------ argmax / softmax
__global__ void argmax_ker(const float* __restrict__ s_as, const float* __restrict__ s_qa,
                           int* __restrict__ a_idx, int* __restrict__ q_idx)
{
  const int t = blockIdx.x * 256 + threadIdx.x;
  if (t >= 8192) return;
  const int b = t >> 10, h = t & 1023;
  {
    const float* p = s_as + (size_t)b * 8192 + h;
    float best = p[0]; int bi = 0;
#pragma unroll
    for (int a = 1; a < 8; ++a) { float v = p[(size_t)a * 1024]; if (v > best) { best = v; bi = a; } }
    a_idx[t] = bi;
  }
  {
    const float* p = s_qa + (size_t)t * 8;
    float best = p[0]; int bi = 0;
#pragma unroll
    for (int a = 1; a < 8; ++a) { float v = p[a]; if (v > best) { best = v; bi = a; } }
    q_idx[t] = bi;
  }
}

__global__ __launch_bounds__(1024) void softmax_ker(
    const float* __restrict__ s_as, const float* __restrict__ s_qa,
    const int* __restrict__ a_idx, const int* __restrict__ q_idx,
    unsigned short* __restrict__ Out)
{
  const int bh = blockIdx.x;                      // b*1024 + h
  const int b = bh >> 10, h = bh & 1023;
  const int j = threadIdx.x;
  __shared__ float red[16];
  __shared__ float sval;
  float u[8];
#pragma unroll
  for (int a = 0; a < 8; ++a) u[a] = s_as[((size_t)(b * 8 + a)) * 1024 + h];
  const int ai = a_idx[bh];
  const float* qrow = s_qa + ((size_t)(b * 1024 + j)) * 8;
  float m = 0.f;
#pragma unroll
  for (int a = 0; a < 8; ++a) m += u[a] * qrow[a];
  if (q_idx[b * 1024 + j] != ai) m -= 1e6f;
  const int lane = j & 63, wid = j >> 6;
  float mx = m;
  for (int off = 32; off; off >>= 1) mx = fmaxf(mx, __shfl_down(mx, off));
  if (lane == 0) red[wid] = mx;
  __syncthreads();
  if (j == 0) { float v = red[0]; for (int i = 1; i < 16; ++i) v = fmaxf(v, red[i]); sval = v; }
  __syncthreads();
  const float MX = sval;
  const float p = __expf(m - MX);
  float sm = p;
  for (int off = 32; off; off >>= 1) sm += __shfl_down(sm, off);
  if (lane == 0) red[wid] = sm;
  __syncthreads();
  if (j == 0) { float v = 0.f; for (int i = 0; i < 16; ++i) v += red[i]; sval = v; }
  __syncthreads();
  Out[(size_t)bh * 1024 + j] = f2bf(p / sval);
}

// ---- conv1 3x3 (Cin=64, Cout=3), channel-major bf16 input, f32 NCHW out,
// all 8 batches: X3T [64][131072], pix = b*16384 + y*128 + x.
__global__ void conv1_ker(const unsigned short* __restrict__ X3T,
                          const float* __restrict__ Wsrc, float* __restrict__ Out)
{
  __shared__ float Wl[9 * 64 * 3];                 // [tap][ci][o]
  for (int i = threadIdx.x; i < 1728; i += 256) {
    int o = i / 576, rem = i - o * 576, ci = rem / 9, tap = rem - ci * 9;
    Wl[(tap * 64 + ci) * 3 + o] = Wsrc[((size_t)(o * 64 + ci)) * 9 + tap];
  }
  __syncthreads();
  const int pg = blockIdx.x * 256 + threadIdx.x;   // 0..131071
  const int b = pg >> 14, pix = pg & 16383, y = pix >> 7, x = pix & 127;
  float acc0 = 0.f, acc1 = 0.f, acc2 = 0.f;
#pragma unroll
  for (int tap = 0; tap < 9; ++tap) {
    const int yy = y + tap / 3 - 1, xx = x + tap % 3 - 1;
    if ((unsigned)yy >= 128u || (unsigned)xx >= 128u) continue;
    const size_t p = (size_t)b * 16384 + (size_t)yy * 128 + xx;
    const float* w = &Wl[tap * 192];
#pragma unroll
    for (int ci = 0; ci < 64; ++ci) {
      float v = bf2f(X3T[(size_t)ci * 131072 + p]);
      acc0 += v * w[ci * 3 + 0];
      acc1 += v * w[ci * 3 + 1];
      acc2 += v * w[ci * 3 + 2];
    }
  }
  const size_t base = (size_t)b * 49152 + (size_t)y * 128 + x;
  Out[base]         = acc0;
  Out[base + 16384] = acc1;
  Out[base + 32768] = acc2;
}

// ================================================================ launch
extern "C" void kernel_launch(void* const* d_in, const int* in_sizes, int n_in,
                              void* d_out, int out_size, void* d_ws, size_t ws_size,
                              hipStream_t stream)
{
  (void)in_sizes; (void)n_in; (void)out_size; (void)ws_size;
  const float* tok    = (const float*)d_in[0];
  const float* supp   = (const float*)d_in[1];
  const float* query  = (const float*)d_in[2];
  const float* qa_W   = (const float*)d_in[3];  const float* qa_b  = (const float*)d_in[4];
  const float* ks_W   = (const float*)d_in[5];  const float* ks_b  = (const float*)d_in[6];
  const float* ka_W   = (const float*)d_in[7];  const float* ka_b  = (const float*)d_in[8];
  const float* vs_W   = (const float*)d_in[9];  const float* vs_b  = (const float*)d_in[10];
  const float* ffn_W1 = (const float*)d_in[11]; const float* ffn_b1= (const float*)d_in[12];
  const float* ffn_W2 = (const float*)d_in[13]; const float* ffn_b2= (const float*)d_in[14];
  const float* up0_W  = (const float*)d_in[15]; const float* up0_b = (const float*)d_in[16];
  const float* up1_W  = (const float*)d_in[17]; const float* up1_b = (const float*)d_in[18];
  const float* c3_W   = (const float*)d_in[19]; const float* c1_W  = (const float*)d_in[20];
  float* out = (float*)d_out;

  float* F = (float*)d_ws;
  // persistent region
  unsigned short* vsWb   = (unsigned short*)(F + 0);
  unsigned short* ffnW1b = (unsigned short*)(F + 131072);
  unsigned short* ffnW2b = (unsigned short*)(F + 655360);
  unsigned short* up0t   = (unsigned short*)(F + 1179648);
  unsigned short* up1t   = (unsigned short*)(F + 1703936);
  unsigned short* c3t    = (unsigned short*)(F + 2228224);
  float* qa    = F + 2375680;
  float* ka    = F + 2408448;
  float* s_as  = F + 2441216;
  float* s_qa  = F + 2506752;
  int*   a_idx = (int*)(F + 2572288);
  int*   q_idx = (int*)(F + 2580480);
  unsigned short* zbuf = (unsigned short*)(F + 2588672);   // 4 KB, memset 0
  // slots (liveness-ordered reuse)
  unsigned short* sqsT  = (unsigned short*)(F + 2589696);      // S1
  unsigned short* dec   = (unsigned short*)(F + 2589696);      // S1
  unsigned short* x3    = (unsigned short*)(F + 2589696);      // S1: [131072][64]
  float* qk             = F + 6784000;                         // S2 head (dead pre-softmax)
  float* kq             = F + 6784000 + 32768;
  float* cas            = F + 6784000 + 65536;
  float* cqa            = F + 6784000 + 65600;
  unsigned short* sqs   = (unsigned short*)(F + 6784000);      // S2
  unsigned short* x3T   = (unsigned short*)(F + 6784000);      // S2: [64][131072]
  unsigned short* suppb = (unsigned short*)(F + 10978304);     // S3
  unsigned short* vsT   = (unsigned short*)(F + 10978304);     // S3
  unsigned short* t0    = (unsigned short*)(F + 10978304);     // S3
  unsigned short* Weff  = (unsigned short*)(F + 10978304);     // S3 (after t0 dies): 524288 shorts = 262144 floats
  float* bias_tap       = F + 10978304 + 262144;               // FIX: past Weff's full 262144-float extent
  unsigned short* vsb   = (unsigned short*)(F + 13075456);     // S4
  unsigned short* attn  = (unsigned short*)(F + 13075456);     // S4
  unsigned short* h1    = (unsigned short*)(F + 15172608);     // S5
  unsigned short* x1    = (unsigned short*)(F + 15172608);     // S5: [8][64][64][512]

  hipMemsetAsync(zbuf, 0, 4096, stream);

  // converts / reorders
  cvt_bf_ker<<<4096, 256, 0, stream>>>(supp,   suppb,  1048576);
  cvt_bf_ker<<<256,  256, 0, stream>>>(vs_W,   vsWb,   65536);
  cvt_bf_ker<<<1024, 256, 0, stream>>>(ffn_W1, ffnW1b, 262144);
  cvt_bf_ker<<<1024, 256, 0, stream>>>(ffn_W2, ffnW2b, 262144);
  reorder_up_bf_ker<<<4096, 256, 0, stream>>>(up0_W, up0t);
  reorder_up_bf_ker<<<4096, 256, 0, stream>>>(up1_W, up1t);
  reorder_c3_bf_ker<<<1152, 256, 0, stream>>>(c3_W, c3t);

  // f32 score path (tiny): qa, ka, then qk = qa@ks_W, kq = ka@qa_W
  gemm_nt_f32_ker<<<dim3(8, 1), 256, 0, stream>>>(tok, qa_W, qa_b, qa, 64, 512, 512);
  gemm_nt_f32_ker<<<dim3(8, 1), 256, 0, stream>>>(tok, ka_W, ka_b, ka, 64, 512, 512);
  nn8_ker<<<64, 512, 0, stream>>>(qa, ks_W, qk);
  nn8_ker<<<64, 512, 0, stream>>>(ka, qa_W, kq);
  score_const_ker<<<1, 64, 0, stream>>>(qa, ka, ks_b, qa_b, cas, cqa);
  scores_both_ker<<<256, 256, 0, stream>>>(qk, kq, supp, query, cas, cqa, s_as, s_qa);

  // vs projection (bf16 MFMA)
  mfma_nt_ker<0><<<dim3(4, 64, 1), 256, 0, stream>>>(suppb, vsWb, vs_b, vsb,
      8192, 512, 512, 0, 0, 0, 0, 0, 0, 0);

  argmax_ker<<<32, 256, 0, stream>>>(s_as, s_qa, a_idx, q_idx);
  softmax_ker<<<8192, 1024, 0, stream>>>(s_as, s_qa, a_idx, q_idx, sqs);

  // transposes for PV operands
  transpose_bf_ker<<<dim3(32, 32, 8), 256, 0, stream>>>(sqs, sqsT, 1024, 1024); // S2->S1
  transpose_bf_ker<<<dim3(16, 32, 8), 256, 0, stream>>>(vsb, vsT, 1024, 512);   // S4->S3

  // attn[b,i,c] = sum_h P[b,h,i] * vs[b,h,c]  (batched MFMA)
  mfma_nt_ker<0><<<dim3(4, 8, 8), 256, 0, stream>>>(sqsT, vsT, nullptr, attn,
      1024, 512, 1024, 0, 1024L*1024, 512L*1024, 1024L*512, 0, 0, 0);

  // FFN
  mfma_nt_ker<0><<<dim3(16, 64, 1), 256, 0, stream>>>(attn, ffnW1b, ffn_b1, h1,
      8192, 2048, 512, 1, 0, 0, 0, 0, 0, 0);
  mfma_nt_ker<0><<<dim3(4, 64, 1), 256, 0, stream>>>(h1, ffnW2b, ffn_b2, dec,
      8192, 512, 2048, 0, 0, 0, 0, 0, 0, 0);

  // dec raw-reinterpret (b,512,32,32) -> NHWC t0 [b][1024][512]
  transpose_bf_ker<<<dim3(32, 16, 8), 256, 0, stream>>>(dec, t0, 512, 1024);    // S1->S3

  // up0: all 4 parities in one launch, scatter to x1 [8][64][64][512]
  mfma_nt_ker<2><<<dim3(4, 64, 4), 256, 0, stream>>>(t0, up0t, up0_b, x1,
      8192, 512, 512, 0, 0, 262144, 0, 10, 5, 2097152L);

  // contracted weights + per-tap bias (t0 dead -> S3 reusable)
  weff_ker<<<dim3(8, 16), 256, 0, stream>>>(c3t, up1t, Weff);
  bias_tap_ker<<<1, 256, 0, stream>>>(c3_W, up1_b, bias_tap);

  // FUSED up1+conv3 -> x3 (all 8 batches, 1024 blocks)
  mfma_upc3_ker<<<dim3(32, 4, 8), 256, 0, stream>>>(x1, Weff, bias_tap, x3, zbuf);

  // x3 [131072][64] -> x3T [64][131072], then conv1 all batches
  transpose_bf_ker<<<dim3(2, 4096, 1), 256, 0, stream>>>(x3, x3T, 131072, 64);
  conv1_ker<<<512, 256, 0, stream>>>(x3T, c1_W, out);
}

// Round 11
// 857.793 us; speedup vs baseline: 7.0682x; 1.2933x over previous
//
#include <hip/hip_runtime.h>

// AgentMatchingDecoder on MI355X — round 11: MFMA-ize weff (round-10's 262 µs
// VALU-serial weight contraction -> 64-block MFMA GEMM, M=64 N=512 K=512/tap).
// Requires up1n[p][i][ci] reorder (K-contiguous B rows), replacing up1t whose
// only consumer was weff. Everything else identical to round 10 (1109 µs).

using short8 = __attribute__((ext_vector_type(8))) short;   // 8 bf16 (4 VGPR)
using f32x4  = __attribute__((ext_vector_type(4))) float;   // MFMA acc

__device__ __forceinline__ unsigned short f2bf(float f) {
  unsigned int u = __float_as_uint(f);
  return (unsigned short)((u + 0x7FFFu + ((u >> 16) & 1u)) >> 16);
}
__device__ __forceinline__ float bf2f(unsigned short h) {
  return __uint_as_float(((unsigned int)h) << 16);
}
__device__ __forceinline__ void stage16(const unsigned short* g, unsigned short* l) {
  __builtin_amdgcn_global_load_lds(
      (const __attribute__((address_space(1))) unsigned int*)g,
      (__attribute__((address_space(3))) unsigned int*)l, 16, 0, 0);
}
// LDS slot swizzle: involution over the 4 16-byte slots of a 64B tile row.
__device__ __forceinline__ int swz(int r) { return (r & 3) ^ ((r >> 2) & 3); }

// ------------------------------------------------------------ converts
__global__ void cvt_bf_ker(const float* __restrict__ in, unsigned short* __restrict__ out, int n4) {
  int i = blockIdx.x * 256 + threadIdx.x;
  if (i >= n4) return;
  float4 v = ((const float4*)in)[i];
  unsigned int lo = (unsigned int)f2bf(v.x) | ((unsigned int)f2bf(v.y) << 16);
  unsigned int hi = (unsigned int)f2bf(v.z) | ((unsigned int)f2bf(v.w) << 16);
  ((uint2*)out)[i] = make_uint2(lo, hi);
}

// up0_W (in=512,out=512,2,2) -> bf16 Wt[p][o][i], p = dy*2+dx
__global__ void reorder_up_bf_ker(const float* __restrict__ W, unsigned short* __restrict__ Wt) {
  int t = blockIdx.x * 256 + threadIdx.x;       // 1,048,576
  int i = t & 511, o = (t >> 9) & 511, p = t >> 18;
  Wt[t] = f2bf(W[((size_t)(i * 512 + o)) * 4 + p]);
}

// up1_W (in=512,out=512,2,2) -> bf16 up1n[p][i][ci] = W[(i*512+ci)*4+p]
// (K=ci contiguous rows for the weff MFMA B-operand; reads are stride-16B)
__global__ void reorder_up_bf_T_ker(const float* __restrict__ W, unsigned short* __restrict__ Wt) {
  int t = blockIdx.x * 256 + threadIdx.x;       // 1,048,576 = p*i*ci
  int ci = t & 511, i = (t >> 9) & 511, p = t >> 18;
  Wt[t] = f2bf(W[((size_t)(i * 512 + ci)) * 4 + p]);
}

// conv3_W (64,512,3,3) -> bf16 Wt[o][tap*512+ci]
__global__ void reorder_c3_bf_ker(const float* __restrict__ W, unsigned short* __restrict__ Wt) {
  int t = blockIdx.x * 256 + threadIdx.x;       // 294,912
  if (t >= 64 * 4608) return;
  int o = t / 4608, rem = t - o * 4608, tap = rem >> 9, ci = rem & 511;
  Wt[t] = f2bf(W[((size_t)(o * 512 + ci)) * 9 + tap]);
}

// --------- Weff via MFMA: Weff[cls][o][slab*512+i] = sum_taps c3·W1
// Grid (4 n-tiles, 16 q=cls*4+slab). Block 256 thr = 4 waves (2m x 2n),
// per-wave 32x64 (2x4 frags of 16x16). M=64 (o), N=512 (i), K=512 per tap.
__global__ __launch_bounds__(256) void weff_mfma_ker(
    const unsigned short* __restrict__ c3t, const unsigned short* __restrict__ up1n,
    unsigned short* __restrict__ Weff)
{
  __shared__ __align__(16) unsigned short As[2][64 * 32];
  __shared__ __align__(16) unsigned short Bs[2][128 * 32];
  const int tid = threadIdx.x, wave = tid >> 6, lane = tid & 63;
  const int wm = wave >> 1, wn = wave & 1;
  const int bn = blockIdx.x * 128;
  const int cls = blockIdx.y >> 2, slab = blockIdx.y & 3;
  const int py = cls >> 1, px = cls & 1, rs = slab >> 1, cs = slab & 1;

  f32x4 zero4 = {0.f, 0.f, 0.f, 0.f};
  f32x4 acc[2][4];
#pragma unroll
  for (int i = 0; i < 2; ++i)
#pragma unroll
    for (int j = 0; j < 4; ++j) acc[i][j] = zero4;

  for (int ky = 0; ky < 3; ++ky) {             // block-uniform tap loop
    int ur = py + ky - 1;
    if (((ur >> 1) + 1 - py) != rs) continue;
    int pu = ur & 1;
    for (int kx = 0; kx < 3; ++kx) {
      int vr = px + kx - 1;
      if (((vr >> 1) + 1 - px) != cs) continue;
      int pv = vr & 1;
      const unsigned short* At = c3t + (ky * 3 + kx) * 512;                  // + o*4608
      const unsigned short* Bt = up1n + (size_t)(pu * 2 + pv) * 262144;      // + i*512

#define STAGE_W(buf, kk)                                                      \
      {                                                                       \
        {                                                                     \
          int rr = tid >> 2, s = tid & 3;                                     \
          stage16(At + (size_t)rr * 4608 + (kk) + ((s ^ swz(rr)) << 3),       \
                  &As[buf][(wave * 64) * 8]);                                 \
        }                                                                     \
        _Pragma("unroll")                                                     \
        for (int qq = 0; qq < 2; ++qq) {                                      \
          int idx = qq * 256 + tid;                                           \
          int rr = idx >> 2, s = idx & 3;                                     \
          stage16(Bt + (size_t)(bn + rr) * 512 + (kk) + ((s ^ swz(rr)) << 3), \
                  &Bs[buf][(qq * 256 + wave * 64) * 8]);                      \
        }                                                                     \
      }

      __syncthreads();                          // LDS reuse guard across taps
      STAGE_W(0, 0);
      __syncthreads();
      int cur = 0;
      for (int t = 0; t < 16; ++t) {            // K = 512 / 32
        if (t < 15) STAGE_W(cur ^ 1, (t + 1) << 5);
        short8 af[2], bfr[4];
#pragma unroll
        for (int mt = 0; mt < 2; ++mt) {
          int r = wm * 32 + mt * 16 + (lane & 15);
          int s = (lane >> 4) ^ swz(r);
          af[mt] = *(const short8*)&As[cur][r * 32 + s * 8];
        }
#pragma unroll
        for (int ntt = 0; ntt < 4; ++ntt) {
          int r = wn * 64 + ntt * 16 + (lane & 15);
          int s = (lane >> 4) ^ swz(r);
          bfr[ntt] = *(const short8*)&Bs[cur][r * 32 + s * 8];
        }
#pragma unroll
        for (int mt = 0; mt < 2; ++mt)
#pragma unroll
          for (int ntt = 0; ntt < 4; ++ntt)
            acc[mt][ntt] = __builtin_amdgcn_mfma_f32_16x16x32_bf16(af[mt], bfr[ntt], acc[mt][ntt], 0, 0, 0);
        __syncthreads();
        cur ^= 1;
      }
#undef STAGE_W
    }
  }
#pragma unroll
  for (int mt = 0; mt < 2; ++mt)
#pragma unroll
    for (int ntt = 0; ntt < 4; ++ntt)
#pragma unroll
      for (int qq = 0; qq < 4; ++qq) {
        int row = wm * 32 + mt * 16 + ((lane >> 4) << 2) + qq;
        int col = bn + wn * 64 + ntt * 16 + (lane & 15);
        Weff[(size_t)cls * 131072 + (size_t)row * 2048 + slab * 512 + col] = f2bf(acc[mt][ntt][qq]);
      }
}

// bias_tap[tap][o] = sum_ci c3_W[o][ci][tap] * up1_b[ci]   (f32 inputs)
__global__ void bias_tap_ker(const float* __restrict__ c3W, const float* __restrict__ up1b,
                             float* __restrict__ bias_tap)
{
  for (int idx = threadIdx.x; idx < 576; idx += 256) {
    int tap = idx >> 6, o = idx & 63;
    float s = 0.f;
    for (int ci = 0; ci < 512; ++ci)
      s += c3W[(size_t)(o * 512 + ci) * 9 + tap] * up1b[ci];
    bias_tap[tap * 64 + o] = s;
  }
}

// ------------------------------------------- f32 GEMM NT (qa/ka only, tiny)
__device__ __forceinline__ void fma16(const float4 av, const float4 bv, float acc[4][4]) {
  acc[0][0] += av.x*bv.x; acc[0][1] += av.x*bv.y; acc[0][2] += av.x*bv.z; acc[0][3] += av.x*bv.w;
  acc[1][0] += av.y*bv.x; acc[1][1] += av.y*bv.y; acc[1][2] += av.y*bv.z; acc[1][3] += av.y*bv.w;
  acc[2][0] += av.z*bv.x; acc[2][1] += av.z*bv.y; acc[2][2] += av.z*bv.z; acc[2][3] += av.z*bv.w;
  acc[3][0] += av.w*bv.x; acc[3][1] += av.w*bv.y; acc[3][2] += av.w*bv.z; acc[3][3] += av.w*bv.w;
}
__global__ __launch_bounds__(256) void gemm_nt_f32_ker(
    const float* __restrict__ A, const float* __restrict__ B,
    const float* __restrict__ bias, float* __restrict__ C, int M, int N, int K)
{
  __shared__ float As[16][68];
  __shared__ float Bs[16][68];
  const int tid = threadIdx.x;
  const int tx = tid & 15, ty = tid >> 4;
  const int bm = blockIdx.y * 64, bn = blockIdx.x * 64;
  const int lr = tid >> 2, lk = (tid & 3) << 2;
  const float* Ap = A + (size_t)(bm + lr) * K + lk;
  const float* Bp = B + (size_t)(bn + lr) * K + lk;
  float acc[4][4] = {};
  for (int k0 = 0; k0 < K; k0 += 16) {
    float4 a4 = *(const float4*)(Ap + k0);
    float4 b4 = *(const float4*)(Bp + k0);
    __syncthreads();
    As[lk+0][lr] = a4.x; As[lk+1][lr] = a4.y; As[lk+2][lr] = a4.z; As[lk+3][lr] = a4.w;
    Bs[lk+0][lr] = b4.x; Bs[lk+1][lr] = b4.y; Bs[lk+2][lr] = b4.z; Bs[lk+3][lr] = b4.w;
    __syncthreads();
#pragma unroll
    for (int k = 0; k < 16; ++k) {
      const float4 av = *(const float4*)&As[k][ty << 2];
      const float4 bv = *(const float4*)&Bs[k][tx << 2];
      fma16(av, bv, acc);
    }
  }
#pragma unroll
  for (int i = 0; i < 4; ++i)
#pragma unroll
    for (int j = 0; j < 4; ++j) {
      const int row = bm + (ty << 2) + i, col = bn + (tx << 2) + j;
      C[(size_t)row * N + col] = acc[i][j] + bias[col];
    }
}

// ---------------------- small NN GEMM: Out[ba,i] = sum_c X[ba,c] * W[c,i]
__global__ void nn8_ker(const float* __restrict__ X, const float* __restrict__ W,
                        float* __restrict__ Out)
{
  const int ba = blockIdx.x;                     // 64 rows
  const int i  = threadIdx.x;                    // 512
  __shared__ float xr[512];
  xr[i] = X[(size_t)ba * 512 + i];
  __syncthreads();
  float s = 0.f;
#pragma unroll 4
  for (int c = 0; c < 512; ++c) s += xr[c] * W[(size_t)c * 512 + i];
  Out[(size_t)ba * 512 + i] = s;
}

// consts: cas[ba]=dot(qa[ba],ks_b), cqa[ba]=dot(ka[ba],qa_b)
__global__ void score_const_ker(const float* __restrict__ qa, const float* __restrict__ ka,
                                const float* __restrict__ ks_b, const float* __restrict__ qa_b,
                                float* __restrict__ cas, float* __restrict__ cqa)
{
  const int t = threadIdx.x;                     // 64
  float s1 = 0.f, s2 = 0.f;
  for (int c = 0; c < 512; ++c) {
    s1 += qa[(size_t)t * 512 + c] * ks_b[c];
    s2 += ka[(size_t)t * 512 + c] * qa_b[c];
  }
  cas[t] = s1; cqa[t] = s2;
}

// scores: s_as[b,a,h] = (qk[b,a]·supp[b,h] + cas)/8 ; s_qa[b,h,a] likewise
__global__ void scores_both_ker(const float* __restrict__ qk, const float* __restrict__ kq,
                                const float* __restrict__ supp, const float* __restrict__ query,
                                const float* __restrict__ cas, const float* __restrict__ cqa,
                                float* __restrict__ s_as, float* __restrict__ s_qa)
{
  const int t = blockIdx.x * 256 + threadIdx.x;  // 65536
  const int a = t & 7, h = (t >> 3) & 1023, b = t >> 13;
  const float* qkp = qk + (size_t)(b * 8 + a) * 512;
  const float* sp  = supp + ((size_t)b * 1024 + h) * 512;
  const float* kqp = kq + (size_t)(b * 8 + a) * 512;
  const float* qp  = query + ((size_t)b * 1024 + h) * 512;
  float s1 = 0.f, s2 = 0.f;
  for (int k = 0; k < 512; k += 4) {
    float4 xv = *(const float4*)(qkp + k), yv = *(const float4*)(sp + k);
    s1 += xv.x*yv.x + xv.y*yv.y + xv.z*yv.z + xv.w*yv.w;
    float4 uv = *(const float4*)(kqp + k), wv = *(const float4*)(qp + k);
    s2 += uv.x*wv.x + uv.y*wv.y + uv.z*wv.z + uv.w*wv.w;
  }
  s_as[((size_t)(b * 8 + a)) * 1024 + h] = 0.125f * (s1 + cas[b * 8 + a]);
  s_qa[((size_t)(b * 1024 + h)) * 8 + a] = 0.125f * (s2 + cqa[b * 8 + a]);
}

// ---------------------------------------------- bf16 MFMA GEMM NT (+scatter)
// 2-phase double-buffered pipeline. BM=BN=128, BK=32; 4 waves, 4x4 frags.
// MODE 0: C[row*N+col], z batches via sA/sB/sC.
// MODE 2: z = ConvT parity (dy=z>>1,dx=z&1), B at z*sB, scatter epilogue.
template<int MODE>
__global__ __launch_bounds__(256) void mfma_nt_ker(
    const unsigned short* __restrict__ A, const unsigned short* __restrict__ B,
    const float* __restrict__ bias, unsigned short* __restrict__ C,
    int M, int N, int K, int relu,
    long sA, long sB, long sC,
    int pixShift, int winShift, long outBS)
{
  (void)M;
  __shared__ __align__(16) unsigned short As[2][128 * 32];
  __shared__ __align__(16) unsigned short Bs[2][128 * 32];
  const int tid = threadIdx.x, wave = tid >> 6, lane = tid & 63;
  const int wm = wave >> 1, wn = wave & 1;
  const int bm = blockIdx.y * 128, bn = blockIdx.x * 128;
  const int z = blockIdx.z;
  const unsigned short* Az = A + (MODE == 2 ? 0 : (size_t)z * sA);
  const unsigned short* Bz = B + (size_t)z * sB;

  f32x4 zero4 = {0.f, 0.f, 0.f, 0.f};
  f32x4 acc[4][4];
#pragma unroll
  for (int i = 0; i < 4; ++i)
#pragma unroll
    for (int j = 0; j < 4; ++j) acc[i][j] = zero4;

#define STAGE_NT(buf, kk)                                                     \
  {                                                                           \
    _Pragma("unroll")                                                         \
    for (int q = 0; q < 2; ++q) {                                             \
      int idx = q * 256 + tid;                                                \
      int rr = idx >> 2, s = idx & 3;                                         \
      stage16(Az + (size_t)(bm + rr) * K + (kk) + ((s ^ swz(rr)) << 3),       \
              &As[buf][(q * 256 + wave * 64) * 8]);                           \
    }                                                                         \
    _Pragma("unroll")                                                         \
    for (int q = 0; q < 2; ++q) {                                             \
      int idx = q * 256 + tid;                                                \
      int rr = idx >> 2, s = idx & 3;                                         \
      stage16(Bz + (size_t)(bn + rr) * K + (kk) + ((s ^ swz(rr)) << 3),       \
              &Bs[buf][(q * 256 + wave * 64) * 8]);                           \
    }                                                                         \
  }

  STAGE_NT(0, 0);
  __syncthreads();                                // buf0 ready
  const int nt = K >> 5;
  int cur = 0;
  for (int t = 0; t < nt; ++t) {
    if (t + 1 < nt) STAGE_NT(cur ^ 1, (t + 1) << 5);   // loads fly under MFMA
    short8 af[4], bfr[4];
#pragma unroll
    for (int mt = 0; mt < 4; ++mt) {
      int r = wm * 64 + mt * 16 + (lane & 15);
      int s = (lane >> 4) ^ swz(r);
      af[mt] = *(const short8*)&As[cur][r * 32 + s * 8];
    }
#pragma unroll
    for (int ntt = 0; ntt < 4; ++ntt) {
      int r = wn * 64 + ntt * 16 + (lane & 15);
      int s = (lane >> 4) ^ swz(r);
      bfr[ntt] = *(const short8*)&Bs[cur][r * 32 + s * 8];
    }
#pragma unroll
    for (int mt = 0; mt < 4; ++mt)
#pragma unroll
      for (int ntt = 0; ntt < 4; ++ntt)
        acc[mt][ntt] = __builtin_amdgcn_mfma_f32_16x16x32_bf16(af[mt], bfr[ntt], acc[mt][ntt], 0, 0, 0);
    __syncthreads();                              // drain next-tile loads
    cur ^= 1;
  }
#undef STAGE_NT

  unsigned short* Cz = C + (MODE == 2 ? 0 : (size_t)z * sC);
  const int pdy = (MODE == 2) ? (z >> 1) : 0;
  const int pdx = (MODE == 2) ? (z & 1) : 0;
#pragma unroll
  for (int mt = 0; mt < 4; ++mt)
#pragma unroll
    for (int ntt = 0; ntt < 4; ++ntt)
#pragma unroll
      for (int q = 0; q < 4; ++q) {
        int row = bm + wm * 64 + mt * 16 + ((lane >> 4) << 2) + q;
        int col = bn + wn * 64 + ntt * 16 + (lane & 15);
        float v = acc[mt][ntt][q];
        if (bias) v += bias[col];
        if (relu) v = fmaxf(v, 0.f);
        if (MODE == 0) {
          Cz[(size_t)row * N + col] = f2bf(v);
        } else {
          int bb = row >> pixShift;
          int pix = row & ((1 << pixShift) - 1);
          int y = pix >> winShift, x = pix & ((1 << winShift) - 1);
          int yy = 2 * y + pdy, xx = 2 * x + pdx;
          long o = (long)bb * outBS + ((long)yy * (2 << winShift) + xx) * (long)N + col;
          Cz[o] = f2bf(v);
        }
      }
}

// --------------- FUSED up1+conv3: per parity class, 2x2-neighborhood GEMM
// x1: [8][64][64][512] bf16; Weff: [4][64][2048] bf16; x3: [8*16384][64] bf16
// grid (32 m-blocks, 4 cls, 8 b); BM=128 px (2 Yc rows x 64 Xc), BN=64, K=2048.
__global__ __launch_bounds__(256) void mfma_upc3_ker(
    const unsigned short* __restrict__ x1, const unsigned short* __restrict__ Weff,
    const float* __restrict__ bias_tap, unsigned short* __restrict__ x3,
    const unsigned short* __restrict__ zbuf)
{
  __shared__ __align__(16) unsigned short As[2][128 * 32];
  __shared__ __align__(16) unsigned short Bs[2][64 * 32];
  __shared__ float btap[576];
  const int tid = threadIdx.x, wave = tid >> 6, lane = tid & 63;
  const int wm = wave >> 1, wn = wave & 1;
  const int mb = blockIdx.x;                     // 0..31
  const int cls = blockIdx.y;                    // 0..3
  const int b = blockIdx.z;                      // 0..7
  const int py = cls >> 1, px = cls & 1;
  for (int i = tid; i < 576; i += 256) btap[i] = bias_tap[i];
  const unsigned short* x1b = x1 + ((size_t)b << 21);       // b*4096*512
  const unsigned short* Wc = Weff + (size_t)cls * 131072;

  f32x4 zero4 = {0.f, 0.f, 0.f, 0.f};
  f32x4 acc[4][2];
#pragma unroll
  for (int i = 0; i < 4; ++i) { acc[i][0] = zero4; acc[i][1] = zero4; }

#define STAGE_UC(buf, kk)                                                     \
  {                                                                           \
    const int slab = (kk) >> 9, i0 = (kk) & 511;                              \
    const int rl = slab >> 1, cl = slab & 1;                                  \
    _Pragma("unroll")                                                         \
    for (int q = 0; q < 2; ++q) {                                             \
      int idx = q * 256 + tid;                                                \
      int rr = idx >> 2, s = idx & 3;                                         \
      int Yc = mb * 2 + (rr >> 6), Xc = rr & 63;                              \
      int yr = Yc + rl + py - 1, xc = Xc + cl + px - 1;                       \
      const unsigned short* src = ((unsigned)yr < 64u && (unsigned)xc < 64u)  \
        ? x1b + (((size_t)yr * 64 + xc) << 9) + i0 + ((s ^ swz(rr)) << 3)     \
        : zbuf + ((idx & 127) << 3);                                          \
      stage16(src, &As[buf][(q * 256 + wave * 64) * 8]);                      \
    }                                                                         \
    {                                                                         \
      int rr = tid >> 2, s = tid & 3;                                         \
      stage16(Wc + (size_t)rr * 2048 + (kk) + ((s ^ swz(rr)) << 3),           \
              &Bs[buf][(wave * 64) * 8]);                                     \
    }                                                                         \
  }

  STAGE_UC(0, 0);
  __syncthreads();
  int cur = 0;
  for (int t = 0; t < 64; ++t) {                 // K = 2048 / 32
    if (t < 63) STAGE_UC(cur ^ 1, (t + 1) << 5);
    short8 af[4], bfr[2];
#pragma unroll
    for (int mt = 0; mt < 4; ++mt) {
      int r = wm * 64 + mt * 16 + (lane & 15);
      int s = (lane >> 4) ^ swz(r);
      af[mt] = *(const short8*)&As[cur][r * 32 + s * 8];
    }
#pragma unroll
    for (int ntt = 0; ntt < 2; ++ntt) {
      int r = wn * 32 + ntt * 16 + (lane & 15);
      int s = (lane >> 4) ^ swz(r);
      bfr[ntt] = *(const short8*)&Bs[cur][r * 32 + s * 8];
    }
#pragma unroll
    for (int mt = 0; mt < 4; ++mt)
#pragma unroll
      for (int ntt = 0; ntt < 2; ++ntt)
        acc[mt][ntt] = __builtin_amdgcn_mfma_f32_16x16x32_bf16(af[mt], bfr[ntt], acc[mt][ntt], 0, 0, 0);
    __syncthreads();
    cur ^= 1;
  }
#undef STAGE_UC

#pragma unroll
  for (int mt = 0; mt < 4; ++mt)
#pragma unroll
    for (int ntt = 0; ntt < 2; ++ntt)
#pragma unroll
      for (int q = 0; q < 4; ++q) {
        int m = wm * 64 + mt * 16 + ((lane >> 4) << 2) + q;
        int o = wn * 32 + ntt * 16 + (lane & 15);
        int Yc = mb * 2 + (m >> 6), Xc = m & 63;
        int Y = 2 * Yc + py, X = 2 * Xc + px;
        float bsum = 0.f;
#pragma unroll
        for (int ky = 0; ky < 3; ++ky) {
          if ((unsigned)(Y + ky - 1) >= 128u) continue;
#pragma unroll
          for (int kx = 0; kx < 3; ++kx)
            if ((unsigned)(X + kx - 1) < 128u) bsum += btap[(ky * 3 + kx) * 64 + o];
        }
        float v = fmaxf(acc[mt][ntt][q] + bsum, 0.f);
        x3[((size_t)b * 16384 + (size_t)Y * 128 + X) * 64 + o] = f2bf(v);
      }
}

// ------------------------------------------------ batched bf16 transpose
__global__ void transpose_bf_ker(const unsigned short* __restrict__ src,
                                 unsigned short* __restrict__ dst, int R, int C)
{
  __shared__ unsigned short tile[32][33];
  const size_t zo = (size_t)blockIdx.z * R * C;
  const int r0 = blockIdx.y * 32, c0 = blockIdx.x * 32;
  const int tx = threadIdx.x & 31, ty = threadIdx.x >> 5;   // 32 x 8
  for (int i = ty; i < 32; i += 8)
    tile[i][tx] = src[zo + (size_t)(r0 + i) * C + c0 + tx];
  __syncthreads();
  for (int i = ty; i < 32; i += 8)
    dst[zo + (size_t)(c0 + i) * R + r0 + tx] = tile[tx][i];
}

// ------------------------------------------------ argmax / softmax
__global__ void argmax_ker(const float* __restrict__ s_as, const float* __restrict__ s_qa,
                           int* __restrict__ a_idx, int* __restrict__ q_idx)
{
  const int t = blockIdx.x * 256 + threadIdx.x;
  if (t >= 8192) return;
  const int b = t >> 10, h = t & 1023;
  {
    const float* p = s_as + (size_t)b * 8192 + h;
    float best = p[0]; int bi = 0;
#pragma unroll
    for (int a = 1; a < 8; ++a) { float v = p[(size_t)a * 1024]; if (v > best) { best = v; bi = a; } }
    a_idx[t] = bi;
  }
  {
    const float* p = s_qa + (size_t)t * 8;
    float best = p[0]; int bi = 0;
#pragma unroll
    for (int a = 1; a < 8; ++a) { float v = p[a]; if (v > best) { best = v; bi = a; } }
    q_idx[t] = bi;
  }
}

__global__ __launch_bounds__(1024) void softmax_ker(
    const float* __restrict__ s_as, const float* __restrict__ s_qa,
    const int* __restrict__ a_idx, const int* __restrict__ q_idx,
    unsigned short* __restrict__ Out)
{
  const int bh = blockIdx.x;                      // b*1024 + h
  const int b = bh >> 10, h = bh & 1023;
  const int j = threadIdx.x;
  __shared__ float red[16];
  __shared__ float sval;
  float u[8];
#pragma unroll
  for (int a = 0; a < 8; ++a) u[a] = s_as[((size_t)(b * 8 + a)) * 1024 + h];
  const int ai = a_idx[bh];
  const float* qrow = s_qa + ((size_t)(b * 1024 + j)) * 8;
  float m = 0.f;
#pragma unroll
  for (int a = 0; a < 8; ++a) m += u[a] * qrow[a];
  if (q_idx[b * 1024 + j] != ai) m -= 1e6f;
  const int lane = j & 63, wid = j >> 6;
  float mx = m;
  for (int off = 32; off; off >>= 1) mx = fmaxf(mx, __shfl_down(mx, off));
  if (lane == 0) red[wid] = mx;
  __syncthreads();
  if (j == 0) { float v = red[0]; for (int i = 1; i < 16; ++i) v = fmaxf(v, red[i]); sval = v; }
  __syncthreads();
  const float MX = sval;
  const float p = __expf(m - MX);
  float sm = p;
  for (int off = 32; off; off >>= 1) sm += __shfl_down(sm, off);
  if (lane == 0) red[wid] = sm;
  __syncthreads();
  if (j == 0) { float v = 0.f; for (int i = 0; i < 16; ++i) v += red[i]; sval = v; }
  __syncthreads();
  Out[(size_t)bh * 1024 + j] = f2bf(p / sval);
}

// ---- conv1 3x3 (Cin=64, Cout=3), channel-major bf16 input, f32 NCHW out,
// all 8 batches: X3T [64][131072], pix = b*16384 + y*128 + x.
__global__ void conv1_ker(const unsigned short* __restrict__ X3T,
                          const float* __restrict__ Wsrc, float* __restrict__ Out)
{
  __shared__ float Wl[9 * 64 * 3];                 // [tap][ci][o]
  for (int i = threadIdx.x; i < 1728; i += 256) {
    int o = i / 576, rem = i - o * 576, ci = rem / 9, tap = rem - ci * 9;
    Wl[(tap * 64 + ci) * 3 + o] = Wsrc[((size_t)(o * 64 + ci)) * 9 + tap];
  }
  __syncthreads();
  const int pg = blockIdx.x * 256 + threadIdx.x;   // 0..131071
  const int b = pg >> 14, pix = pg & 16383, y = pix >> 7, x = pix & 127;
  float acc0 = 0.f, acc1 = 0.f, acc2 = 0.f;
#pragma unroll
  for (int tap = 0; tap < 9; ++tap) {
    const int yy = y + tap / 3 - 1, xx = x + tap % 3 - 1;
    if ((unsigned)yy >= 128u || (unsigned)xx >= 128u) continue;
    const size_t p = (size_t)b * 16384 + (size_t)yy * 128 + xx;
    const float* w = &Wl[tap * 192];
#pragma unroll
    for (int ci = 0; ci < 64; ++ci) {
      float v = bf2f(X3T[(size_t)ci * 131072 + p]);
      acc0 += v * w[ci * 3 + 0];
      acc1 += v * w[ci * 3 + 1];
      acc2 += v * w[ci * 3 + 2];
    }
  }
  const size_t base = (size_t)b * 49152 + (size_t)y * 128 + x;
  Out[base]         = acc0;
  Out[base + 16384] = acc1;
  Out[base + 32768] = acc2;
}

// ================================================================ launch
extern "C" void kernel_launch(void* const* d_in, const int* in_sizes, int n_in,
                              void* d_out, int out_size, void* d_ws, size_t ws_size,
                              hipStream_t stream)
{
  (void)in_sizes; (void)n_in; (void)out_size; (void)ws_size;
  const float* tok    = (const float*)d_in[0];
  const float* supp   = (const float*)d_in[1];
  const float* query  = (const float*)d_in[2];
  const float* qa_W   = (const float*)d_in[3];  const float* qa_b  = (const float*)d_in[4];
  const float* ks_W   = (const float*)d_in[5];  const float* ks_b  = (const float*)d_in[6];
  const float* ka_W   = (const float*)d_in[7];  const float* ka_b  = (const float*)d_in[8];
  const float* vs_W   = (const float*)d_in[9];  const float* vs_b  = (const float*)d_in[10];
  const float* ffn_W1 = (const float*)d_in[11]; const float* ffn_b1= (const float*)d_in[12];
  const float* ffn_W2 = (const float*)d_in[13]; const float* ffn_b2= (const float*)d_in[14];
  const float* up0_W  = (const float*)d_in[15]; const float* up0_b = (const float*)d_in[16];
  const float* up1_W  = (const float*)d_in[17]; const float* up1_b = (const float*)d_in[18];
  const float* c3_W   = (const float*)d_in[19]; const float* c1_W  = (const float*)d_in[20];
  float* out = (float*)d_out;

  float* F = (float*)d_ws;
  // persistent region
  unsigned short* vsWb   = (unsigned short*)(F + 0);
  unsigned short* ffnW1b = (unsigned short*)(F + 131072);
  unsigned short* ffnW2b = (unsigned short*)(F + 655360);
  unsigned short* up0t   = (unsigned short*)(F + 1179648);
  unsigned short* up1n   = (unsigned short*)(F + 1703936);   // [p][i][ci] (weff B-operand)
  unsigned short* c3t    = (unsigned short*)(F + 2228224);
  float* qa    = F + 2375680;
  float* ka    = F + 2408448;
  float* s_as  = F + 2441216;
  float* s_qa  = F + 2506752;
  int*   a_idx = (int*)(F + 2572288);
  int*   q_idx = (int*)(F + 2580480);
  unsigned short* zbuf = (unsigned short*)(F + 2588672);   // 4 KB, memset 0
  // slots (liveness-ordered reuse)
  unsigned short* sqsT  = (unsigned short*)(F + 2589696);      // S1
  unsigned short* dec   = (unsigned short*)(F + 2589696);      // S1
  unsigned short* x3    = (unsigned short*)(F + 2589696);      // S1: [131072][64]
  float* qk             = F + 6784000;                         // S2 head (dead pre-softmax)
  float* kq             = F + 6784000 + 32768;
  float* cas            = F + 6784000 + 65536;
  float* cqa            = F + 6784000 + 65600;
  unsigned short* sqs   = (unsigned short*)(F + 6784000);      // S2
  unsigned short* x3T   = (unsigned short*)(F + 6784000);      // S2: [64][131072]
  unsigned short* suppb = (unsigned short*)(F + 10978304);     // S3
  unsigned short* vsT   = (unsigned short*)(F + 10978304);     // S3
  unsigned short* t0    = (unsigned short*)(F + 10978304);     // S3
  unsigned short* Weff  = (unsigned short*)(F + 10978304);     // S3 (after t0 dies): 524288 shorts = 262144 floats
  float* bias_tap       = F + 10978304 + 262144;               // past Weff's full extent
  unsigned short* vsb   = (unsigned short*)(F + 13075456);     // S4
  unsigned short* attn  = (unsigned short*)(F + 13075456);     // S4
  unsigned short* h1    = (unsigned short*)(F + 15172608);     // S5
  unsigned short* x1    = (unsigned short*)(F + 15172608);     // S5: [8][64][64][512]

  hipMemsetAsync(zbuf, 0, 4096, stream);

  // converts / reorders
  cvt_bf_ker<<<4096, 256, 0, stream>>>(supp,   suppb,  1048576);
  cvt_bf_ker<<<256,  256, 0, stream>>>(vs_W,   vsWb,   65536);
  cvt_bf_ker<<<1024, 256, 0, stream>>>(ffn_W1, ffnW1b, 262144);
  cvt_bf_ker<<<1024, 256, 0, stream>>>(ffn_W2, ffnW2b, 262144);
  reorder_up_bf_ker<<<4096, 256, 0, stream>>>(up0_W, up0t);
  reorder_up_bf_T_ker<<<4096, 256, 0, stream>>>(up1_W, up1n);
  reorder_c3_bf_ker<<<1152, 256, 0, stream>>>(c3_W, c3t);

  // f32 score path (tiny): qa, ka, then qk = qa@ks_W, kq = ka@qa_W
  gemm_nt_f32_ker<<<dim3(8, 1), 256, 0, stream>>>(tok, qa_W, qa_b, qa, 64, 512, 512);
  gemm_nt_f32_ker<<<dim3(8, 1), 256, 0, stream>>>(tok, ka_W, ka_b, ka, 64, 512, 512);
  nn8_ker<<<64, 512, 0, stream>>>(qa, ks_W, qk);
  nn8_ker<<<64, 512, 0, stream>>>(ka, qa_W, kq);
  score_const_ker<<<1, 64, 0, stream>>>(qa, ka, ks_b, qa_b, cas, cqa);
  scores_both_ker<<<256, 256, 0, stream>>>(qk, kq, supp, query, cas, cqa, s_as, s_qa);

  // vs projection (bf16 MFMA)
  mfma_nt_ker<0><<<dim3(4, 64, 1), 256, 0, stream>>>(suppb, vsWb, vs_b, vsb,
      8192, 512, 512, 0, 0, 0, 0, 0, 0, 0);

  argmax_ker<<<32, 256, 0, stream>>>(s_as, s_qa, a_idx, q_idx);
  softmax_ker<<<8192, 1024, 0, stream>>>(s_as, s_qa, a_idx, q_idx, sqs);

  // transposes for PV operands
  transpose_bf_ker<<<dim3(32, 32, 8), 256, 0, stream>>>(sqs, sqsT, 1024, 1024); // S2->S1
  transpose_bf_ker<<<dim3(16, 32, 8), 256, 0, stream>>>(vsb, vsT, 1024, 512);   // S4->S3

  // attn[b,i,c] = sum_h P[b,h,i] * vs[b,h,c]  (batched MFMA)
  mfma_nt_ker<0><<<dim3(4, 8, 8), 256, 0, stream>>>(sqsT, vsT, nullptr, attn,
      1024, 512, 1024, 0, 1024L*1024, 512L*1024, 1024L*512, 0, 0, 0);

  // FFN
  mfma_nt_ker<0><<<dim3(16, 64, 1), 256, 0, stream>>>(attn, ffnW1b, ffn_b1, h1,
      8192, 2048, 512, 1, 0, 0, 0, 0, 0, 0);
  mfma_nt_ker<0><<<dim3(4, 64, 1), 256, 0, stream>>>(h1, ffnW2b, ffn_b2, dec,
      8192, 512, 2048, 0, 0, 0, 0, 0, 0, 0);

  // dec raw-reinterpret (b,512,32,32) -> NHWC t0 [b][1024][512]
  transpose_bf_ker<<<dim3(32, 16, 8), 256, 0, stream>>>(dec, t0, 512, 1024);    // S1->S3

  // up0: all 4 parities in one launch, scatter to x1 [8][64][64][512]
  mfma_nt_ker<2><<<dim3(4, 64, 4), 256, 0, stream>>>(t0, up0t, up0_b, x1,
      8192, 512, 512, 0, 0, 262144, 0, 10, 5, 2097152L);

  // contracted weights (MFMA) + per-tap bias (t0 dead -> S3 reusable)
  weff_mfma_ker<<<dim3(4, 16), 256, 0, stream>>>(c3t, up1n, Weff);
  bias_tap_ker<<<1, 256, 0, stream>>>(c3_W, up1_b, bias_tap);

  // FUSED up1+conv3 -> x3 (all 8 batches, 1024 blocks)
  mfma_upc3_ker<<<dim3(32, 4, 8), 256, 0, stream>>>(x1, Weff, bias_tap, x3, zbuf);

  // x3 [131072][64] -> x3T [64][131072], then conv1 all batches
  transpose_bf_ker<<<dim3(2, 4096, 1), 256, 0, stream>>>(x3, x3T, 131072, 64);
  conv1_ker<<<512, 256, 0, stream>>>(x3T, c1_W, out);
}